// Round 14
// baseline (3399.710 us; speedup 1.0000x reference)
//
#include <hip/hip_runtime.h>
#include <hip/hip_bf16.h>
#include <cstdint>
#include <cstddef>

// ============================================================================
// FastSpeech2 forward on MI355X. Round 14.
//  - attn_k (encoder): Qs/KT rows padded 64->68 floats. r13 counters showed
//    4.85M LDS bank conflicts: row stride 64 put every wave's float4 staging
//    store into ONE 4-bank group (64-way). Stride 68 reaches the 8-way HW
//    floor. Layout-only change -> bit-identical math -> duration-safe.
//  - Cross-attention uses attn_bf2_k: the r10-verified 32KB aliased-LDS
//    variant at 4 blk/CU. CA's K+V^T footprint is 64KB/(b,h) -> 1MB/XCD,
//    L2-safe at high occupancy (r10's thrash was SA-only). SA stays on the
//    proven 2-blk kernel.
//  Everything else identical to r13 (passed, absmax 0.0117).
// ============================================================================

#define B_ 32
#define T_ 256
#define D_ 256
#define NH_ 4
#define FF_ 1024
#define MAXBUF_ 1024
#define NMEL_ 80

typedef __attribute__((ext_vector_type(8))) short short8;
typedef __attribute__((ext_vector_type(4))) float f32x4;

__device__ __forceinline__ unsigned short f2bf(float x) {
  unsigned int u = __float_as_uint(x);
  return (unsigned short)((u + 0x7fffu + ((u >> 16) & 1u)) >> 16);
}
__device__ __forceinline__ float bf2f(unsigned short h) {
  return __uint_as_float(((unsigned int)h) << 16);
}

#define GLD16(g, s)                                                         \
  __builtin_amdgcn_global_load_lds(                                         \
      (__attribute__((address_space(1))) void*)(g),                         \
      (__attribute__((address_space(3))) void*)(s), 16, 0, 0)

// f32 -> bf16 bulk convert (n % 1024 == 0)
__global__ void cvt_k(const float* __restrict__ in, unsigned short* __restrict__ out, int n)
{
  int i = (blockIdx.x * 256 + threadIdx.x) * 4;
  if (i >= n) return;
  float4 v = *(const float4*)(in + i);
  unsigned short o[4] = {f2bf(v.x), f2bf(v.y), f2bf(v.z), f2bf(v.w)};
  *(ushort4*)(out + i) = *(ushort4*)o;
}

// ---------------------------------------------------------------------------
// Mel-head GEMM: A is bf16, W/bias f32, f32 accumulate/output. 64x64 tile.
// ---------------------------------------------------------------------------
__global__ __launch_bounds__(256) void gemm_kb_k(
    const unsigned short* __restrict__ A, const float* __restrict__ W,
    const float* __restrict__ bias, float* __restrict__ C,
    int M, int N, int K)
{
  __shared__ float As[16][64];
  __shared__ float Ws[16][64];
  const int tid = threadIdx.x;
  const int tx = tid & 15, ty = tid >> 4;
  const int bm = blockIdx.x * 64, bn = blockIdx.y * 64;
  const int lm = tid & 63, lk = tid >> 6;
  float acc[4][4] = {{0.f,0.f,0.f,0.f},{0.f,0.f,0.f,0.f},{0.f,0.f,0.f,0.f},{0.f,0.f,0.f,0.f}};
  const bool aok = (bm + lm) < M;
  const bool wok = (bn + lm) < N;
  const unsigned short* Ap = A + (size_t)(bm + lm) * K + lk * 4;
  const float* Wp = W + (size_t)(bn + lm) * K + lk * 4;
  for (int k0 = 0; k0 < K; k0 += 16) {
    float4 av = make_float4(0.f, 0.f, 0.f, 0.f);
    float4 wv = make_float4(0.f, 0.f, 0.f, 0.f);
    if (aok) {
      ushort4 au = *(const ushort4*)(Ap + k0);
      av.x = bf2f(au.x); av.y = bf2f(au.y); av.z = bf2f(au.z); av.w = bf2f(au.w);
    }
    if (wok) wv = *(const float4*)(Wp + k0);
    As[lk*4+0][lm] = av.x; As[lk*4+1][lm] = av.y; As[lk*4+2][lm] = av.z; As[lk*4+3][lm] = av.w;
    Ws[lk*4+0][lm] = wv.x; Ws[lk*4+1][lm] = wv.y; Ws[lk*4+2][lm] = wv.z; Ws[lk*4+3][lm] = wv.w;
    __syncthreads();
#pragma unroll
    for (int kk = 0; kk < 16; ++kk) {
      float4 a4 = *(const float4*)&As[kk][ty * 4];
      float4 b4 = *(const float4*)&Ws[kk][tx * 4];
      float aa[4] = {a4.x, a4.y, a4.z, a4.w};
      float bb[4] = {b4.x, b4.y, b4.z, b4.w};
#pragma unroll
      for (int i = 0; i < 4; ++i)
#pragma unroll
        for (int j = 0; j < 4; ++j)
          acc[i][j] += aa[i] * bb[j];
    }
    __syncthreads();
  }
#pragma unroll
  for (int i = 0; i < 4; ++i) {
    int gm = bm + ty * 4 + i;
    if (gm >= M) continue;
#pragma unroll
    for (int j = 0; j < 4; ++j) {
      int gn = bn + tx * 4 + j;
      if (gn >= N) continue;
      C[(size_t)gm * N + gn] = acc[i][j] + bias[gn];
    }
  }
}

// ---------------------------------------------------------------------------
// Split-K partial GEMM + fixed-order reduce (optional gelu) — unchanged.
// ---------------------------------------------------------------------------
__global__ __launch_bounds__(256, 2) void gemm2p_k(
    const float* __restrict__ A, const float* __restrict__ W,
    float* __restrict__ Dst, float* __restrict__ Palt,
    int M, int N, int kChunk, int Ktot)
{
  __shared__ float As[16][128];
  __shared__ float Bs[16][128];
  const int tid = threadIdx.x;
  const int tx = tid & 15, ty = tid >> 4;
  const int bm = blockIdx.x * 128, bn = blockIdx.y * 128;
  const int z = blockIdx.z;
  const int r = tid & 127, ks = (tid >> 7) * 8;
  f32x4 acc[8][2];
#pragma unroll
  for (int i = 0; i < 8; ++i) {
    acc[i][0] = (f32x4){0.f, 0.f, 0.f, 0.f};
    acc[i][1] = (f32x4){0.f, 0.f, 0.f, 0.f};
  }
  const float* Ap = A + (size_t)(bm + r) * Ktot + z * kChunk + ks;
  const float* Wp = W + (size_t)(bn + r) * Ktot + z * kChunk + ks;
  for (int k0 = 0; k0 < kChunk; k0 += 16) {
    float4 a0 = *(const float4*)(Ap + k0);
    float4 a1 = *(const float4*)(Ap + k0 + 4);
    float4 w0 = *(const float4*)(Wp + k0);
    float4 w1 = *(const float4*)(Wp + k0 + 4);
    __syncthreads();
    As[ks+0][r] = a0.x; As[ks+1][r] = a0.y; As[ks+2][r] = a0.z; As[ks+3][r] = a0.w;
    As[ks+4][r] = a1.x; As[ks+5][r] = a1.y; As[ks+6][r] = a1.z; As[ks+7][r] = a1.w;
    Bs[ks+0][r] = w0.x; Bs[ks+1][r] = w0.y; Bs[ks+2][r] = w0.z; Bs[ks+3][r] = w0.w;
    Bs[ks+4][r] = w1.x; Bs[ks+5][r] = w1.y; Bs[ks+6][r] = w1.z; Bs[ks+7][r] = w1.w;
    __syncthreads();
#pragma unroll
    for (int kk = 0; kk < 16; ++kk) {
      f32x4 bA = *(const f32x4*)&Bs[kk][tx * 4];
      f32x4 bB = *(const f32x4*)&Bs[kk][tx * 4 + 64];
      float4 aA = *(const float4*)&As[kk][ty * 4];
      float4 aB = *(const float4*)&As[kk][ty * 4 + 64];
      float av[8] = {aA.x, aA.y, aA.z, aA.w, aB.x, aB.y, aB.z, aB.w};
#pragma unroll
      for (int i = 0; i < 8; ++i) {
        acc[i][0] += bA * av[i];
        acc[i][1] += bB * av[i];
      }
    }
  }
  float* Out = (z == 0) ? Dst : (Palt + (size_t)(z - 1) * ((size_t)M * N));
#pragma unroll
  for (int i = 0; i < 8; ++i) {
    int gm = bm + (i >> 2) * 64 + ty * 4 + (i & 3);
#pragma unroll
    for (int half = 0; half < 2; ++half) {
      int gn = bn + half * 64 + tx * 4;
      float4 o;
      o.x = acc[i][half][0]; o.y = acc[i][half][1];
      o.z = acc[i][half][2]; o.w = acc[i][half][3];
      *(float4*)(Out + (size_t)gm * N + gn) = o;
    }
  }
}

__global__ __launch_bounds__(256) void rsum_k(
    float* __restrict__ C, const float* __restrict__ Palt,
    const float* __restrict__ bias, int Sm1, int N, size_t MN, int epi)
{
  size_t i = ((size_t)blockIdx.x * 256 + threadIdx.x) * 4;
  if (i >= MN) return;
  float4 a = *(const float4*)(C + i);
  for (int s = 0; s < Sm1; ++s) {
    float4 b = *(const float4*)(Palt + (size_t)s * MN + i);
    a.x += b.x; a.y += b.y; a.z += b.z; a.w += b.w;
  }
  int col = (int)(i % (size_t)N);
  a.x += bias[col + 0]; a.y += bias[col + 1];
  a.z += bias[col + 2]; a.w += bias[col + 3];
  if (epi == 1) {
    a.x = 0.5f * a.x * (1.0f + erff(a.x * 0.70710678118654752f));
    a.y = 0.5f * a.y * (1.0f + erff(a.y * 0.70710678118654752f));
    a.z = 0.5f * a.z * (1.0f + erff(a.z * 0.70710678118654752f));
    a.w = 0.5f * a.w * (1.0f + erff(a.w * 0.70710678118654752f));
  }
  *(float4*)(C + i) = a;
}

// ---------------------------------------------------------------------------
// fp32 flash attention (encoder; duration path). Qs/KT rows padded to 68
// floats: staging stores reach the 8-way LDS floor (was 64-way at stride 64).
// Math bit-identical to r13.
// ---------------------------------------------------------------------------
__global__ __launch_bounds__(256) void attn_k(
    const float* __restrict__ Qp, int qStride,
    const float* __restrict__ Kp, int kStride,
    const float* __restrict__ Vp, int vStride,
    float* __restrict__ Op, int Tq, int Tkv,
    const int* __restrict__ lengths)
{
  const int b = blockIdx.z, h = blockIdx.y, qt = blockIdx.x;
  const int tid = threadIdx.x;
  const int tx = tid & 15, ty = tid >> 4;
  const int lr = tid & 63, lq = tid >> 6;

  __shared__ __align__(16) float Qs[64][68];
  __shared__ __align__(16) float KT[64][68];
  __shared__ float Sm[64][65];

  {
    const float* q = Qp + (size_t)(b * Tq + qt * 64 + lr) * qStride + h * 64 + lq * 16;
    float4 v0 = ((const float4*)q)[0];
    float4 v1 = ((const float4*)q)[1];
    float4 v2 = ((const float4*)q)[2];
    float4 v3 = ((const float4*)q)[3];
    *(float4*)&Qs[lr][lq*16 + 0]  = v0;
    *(float4*)&Qs[lr][lq*16 + 4]  = v1;
    *(float4*)&Qs[lr][lq*16 + 8]  = v2;
    *(float4*)&Qs[lr][lq*16 + 12] = v3;
  }

  float m_reg[4], l_reg[4], o[4][4];
#pragma unroll
  for (int i = 0; i < 4; ++i) {
    m_reg[i] = -INFINITY; l_reg[i] = 0.f;
#pragma unroll
    for (int j = 0; j < 4; ++j) o[i][j] = 0.f;
  }

  const int len_b = lengths ? lengths[b] : 0x7fffffff;
  const int nkt = Tkv >> 6;

  float4 kreg[4], vreg[4];
  {
    const float* kp = Kp + (size_t)(b * Tkv + lr) * kStride + h * 64 + lq * 16;
    kreg[0] = ((const float4*)kp)[0]; kreg[1] = ((const float4*)kp)[1];
    kreg[2] = ((const float4*)kp)[2]; kreg[3] = ((const float4*)kp)[3];
    const float* vp = Vp + (size_t)(b * Tkv + lr) * vStride + h * 64 + lq * 16;
    vreg[0] = ((const float4*)vp)[0]; vreg[1] = ((const float4*)vp)[1];
    vreg[2] = ((const float4*)vp)[2]; vreg[3] = ((const float4*)vp)[3];
  }

  for (int kt = 0; kt < nkt; ++kt) {
    __syncthreads();
    {
#pragma unroll
      for (int u = 0; u < 4; ++u) {
        KT[lq*16 + u*4 + 0][lr] = kreg[u].x;
        KT[lq*16 + u*4 + 1][lr] = kreg[u].y;
        KT[lq*16 + u*4 + 2][lr] = kreg[u].z;
        KT[lq*16 + u*4 + 3][lr] = kreg[u].w;
      }
    }
    if (kt + 1 < nkt) {
      const float* kp = Kp + (size_t)(b * Tkv + (kt + 1) * 64 + lr) * kStride + h * 64 + lq * 16;
      kreg[0] = ((const float4*)kp)[0]; kreg[1] = ((const float4*)kp)[1];
      kreg[2] = ((const float4*)kp)[2]; kreg[3] = ((const float4*)kp)[3];
    }
    __syncthreads();

    float s[4][4] = {{0.f,0.f,0.f,0.f},{0.f,0.f,0.f,0.f},{0.f,0.f,0.f,0.f},{0.f,0.f,0.f,0.f}};
#pragma unroll
    for (int d4 = 0; d4 < 16; ++d4) {
      float4 qv[4], kv[4];
#pragma unroll
      for (int i = 0; i < 4; ++i) qv[i] = *(const float4*)&Qs[ty*4 + i][d4*4];
#pragma unroll
      for (int dd = 0; dd < 4; ++dd) kv[dd] = *(const float4*)&KT[d4*4 + dd][tx*4];
#pragma unroll
      for (int i = 0; i < 4; ++i) {
        s[i][0] += qv[i].x*kv[0].x + qv[i].y*kv[1].x + qv[i].z*kv[2].x + qv[i].w*kv[3].x;
        s[i][1] += qv[i].x*kv[0].y + qv[i].y*kv[1].y + qv[i].z*kv[2].y + qv[i].w*kv[3].y;
        s[i][2] += qv[i].x*kv[0].z + qv[i].y*kv[1].z + qv[i].z*kv[2].z + qv[i].w*kv[3].z;
        s[i][3] += qv[i].x*kv[0].w + qv[i].y*kv[1].w + qv[i].z*kv[2].w + qv[i].w*kv[3].w;
      }
    }

    float alpha[4];
#pragma unroll
    for (int i = 0; i < 4; ++i) {
      float pm = -INFINITY;
#pragma unroll
      for (int j = 0; j < 4; ++j) {
        int kg = kt * 64 + tx * 4 + j;
        float v = s[i][j] * 0.125f;
        if (kg >= len_b) v = -1e9f;
        s[i][j] = v;
        pm = fmaxf(pm, v);
      }
#pragma unroll
      for (int off = 1; off < 16; off <<= 1) pm = fmaxf(pm, __shfl_xor(pm, off));
      float mn = fmaxf(m_reg[i], pm);
      alpha[i] = expf(m_reg[i] - mn);
      float ls = 0.f;
#pragma unroll
      for (int j = 0; j < 4; ++j) {
        float p = expf(s[i][j] - mn);
        Sm[ty*4 + i][tx*4 + j] = p;
        ls += p;
      }
#pragma unroll
      for (int off = 1; off < 16; off <<= 1) ls += __shfl_xor(ls, off);
      l_reg[i] = l_reg[i] * alpha[i] + ls;
      m_reg[i] = mn;
    }
    __syncthreads();

    {
      *(float4*)&KT[lr][lq*16 + 0]  = vreg[0];
      *(float4*)&KT[lr][lq*16 + 4]  = vreg[1];
      *(float4*)&KT[lr][lq*16 + 8]  = vreg[2];
      *(float4*)&KT[lr][lq*16 + 12] = vreg[3];
    }
    if (kt + 1 < nkt) {
      const float* vp = Vp + (size_t)(b * Tkv + (kt + 1) * 64 + lr) * vStride + h * 64 + lq * 16;
      vreg[0] = ((const float4*)vp)[0]; vreg[1] = ((const float4*)vp)[1];
      vreg[2] = ((const float4*)vp)[2]; vreg[3] = ((const float4*)vp)[3];
    }
    __syncthreads();

#pragma unroll
    for (int i = 0; i < 4; ++i) {
      o[i][0] *= alpha[i]; o[i][1] *= alpha[i]; o[i][2] *= alpha[i]; o[i][3] *= alpha[i];
    }
#pragma unroll 8
    for (int c = 0; c < 64; ++c) {
      float4 vv = *(const float4*)&KT[c][tx * 4];
#pragma unroll
      for (int i = 0; i < 4; ++i) {
        float p = Sm[ty*4 + i][c];
        o[i][0] += p * vv.x; o[i][1] += p * vv.y; o[i][2] += p * vv.z; o[i][3] += p * vv.w;
      }
    }
  }

#pragma unroll
  for (int i = 0; i < 4; ++i) {
    float inv = 1.f / l_reg[i];
    float4 r;
    r.x = o[i][0] * inv; r.y = o[i][1] * inv; r.z = o[i][2] * inv; r.w = o[i][3] * inv;
    *(float4*)(Op + (size_t)(b * Tq + qt * 64 + ty * 4 + i) * 256 + h * 64 + tx * 4) = r;
  }
}

// ---------------------------------------------------------------------------
// bf16 MFMA GEMM — unchanged.
// ---------------------------------------------------------------------------
__global__ __launch_bounds__(256) void gemm_bf_k(
    const unsigned short* __restrict__ A, const unsigned short* __restrict__ W,
    const float* __restrict__ bias, unsigned short* __restrict__ C,
    int M, int N, int K, int epi)
{
  __shared__ __align__(16) short As[128 * 32];
  __shared__ __align__(16) short Bs[128 * 32];
  const int tid = threadIdx.x;
  const int lane = tid & 63, w = tid >> 6;
  const int g = lane >> 4, li = lane & 15;
  const int wr = (w >> 1) * 64, wc = (w & 1) * 64;
  const int bm = blockIdx.x * 128, bn = blockIdx.y * 128;

  f32x4 acc[4][4];
#pragma unroll
  for (int m = 0; m < 4; ++m)
#pragma unroll
    for (int n = 0; n < 4; ++n)
      acc[m][n] = (f32x4){0.f, 0.f, 0.f, 0.f};

  const int srow = tid >> 2, scol = (tid & 3) * 8;
  const unsigned short* Ag = A + (size_t)(bm + srow) * K + scol;
  const unsigned short* Wg = W + (size_t)(bn + srow) * K + scol;

  for (int k0 = 0; k0 < K; k0 += 32) {
    __syncthreads();
    GLD16(Ag + k0, &As[tid * 8]);
    GLD16(Ag + k0 + (size_t)64 * K, &As[tid * 8 + 2048]);
    GLD16(Wg + k0, &Bs[tid * 8]);
    GLD16(Wg + k0 + (size_t)64 * K, &Bs[tid * 8 + 2048]);
    __syncthreads();
    short8 af[4], bf[4];
#pragma unroll
    for (int m = 0; m < 4; ++m) af[m] = *(const short8*)&As[(wr + m * 16 + li) * 32 + g * 8];
#pragma unroll
    for (int n = 0; n < 4; ++n) bf[n] = *(const short8*)&Bs[(wc + n * 16 + li) * 32 + g * 8];
#pragma unroll
    for (int m = 0; m < 4; ++m)
#pragma unroll
      for (int n = 0; n < 4; ++n)
        acc[m][n] = __builtin_amdgcn_mfma_f32_16x16x32_bf16(af[m], bf[n], acc[m][n], 0, 0, 0);
  }

#pragma unroll
  for (int m = 0; m < 4; ++m) {
#pragma unroll
    for (int n = 0; n < 4; ++n) {
      int col = bn + wc + n * 16 + li;
      float bv = bias[col];
#pragma unroll
      for (int r = 0; r < 4; ++r) {
        int row = bm + wr + m * 16 + g * 4 + r;
        float v = acc[m][n][r] + bv;
        if (epi == 1) v = 0.5f * v * (1.0f + erff(v * 0.70710678118654752f));
        C[(size_t)row * N + col] = f2bf(v);
      }
    }
  }
}

// ---------------------------------------------------------------------------
// V transpose to global — unchanged.
// ---------------------------------------------------------------------------
__global__ __launch_bounds__(256) void trv_k(
    const unsigned short* __restrict__ V, int vStride,
    unsigned short* __restrict__ VT, int Tkv)
{
  const int kt = blockIdx.x, h = blockIdx.y, b = blockIdx.z;
  __shared__ short t[64][65];
  const int tid = threadIdx.x;
  const int r0 = tid >> 3, seg = tid & 7;
#pragma unroll
  for (int i = 0; i < 2; ++i) {
    int r = r0 + i * 32;
    short8 v = *(const short8*)(V + (size_t)(b * Tkv + kt * 64 + r) * vStride + h * 64 + seg * 8);
    *(short8*)&t[r][seg * 8] = v;
  }
  __syncthreads();
#pragma unroll
  for (int i = 0; i < 2; ++i) {
    int d = r0 + i * 32;
    int k0 = seg * 8;
    short o[8];
#pragma unroll
    for (int j = 0; j < 8; ++j) o[j] = t[k0 + j][d];
    *(short8*)(VT + ((size_t)(b * NH_ + h) * 64 + d) * Tkv + kt * 64 + k0) = *(short8*)o;
  }
}

// ---------------------------------------------------------------------------
// bf16 MFMA flash attention, SA variant: 48KB LDS, 2 blk/CU (L2-safe),
// prefetch. Unchanged from r13.
// ---------------------------------------------------------------------------
__global__ __launch_bounds__(256, 2) void attn_bf_k(
    const unsigned short* __restrict__ Qp, int qStride,
    const unsigned short* __restrict__ Kp, int kStride,
    const unsigned short* __restrict__ VTg,
    unsigned short* __restrict__ Op, int Tq, int Tkv)
{
  int b, h, qt;
  {
    const int nqt = gridDim.x, nh = gridDim.y, nbh = gridDim.y * gridDim.z;
    if ((nbh & 7) == 0) {
      int linear = blockIdx.x + nqt * (blockIdx.y + gridDim.y * blockIdx.z);
      int xcd = linear & 7, idx = linear >> 3;
      int bh = xcd * (nbh >> 3) + idx / nqt;
      qt = idx - (idx / nqt) * nqt;
      h = bh % nh; b = bh / nh;
    } else { qt = blockIdx.x; h = blockIdx.y; b = blockIdx.z; }
  }
  const int tid = threadIdx.x;
  const int lane = tid & 63, w = tid >> 6;
  const int g = lane >> 4, li = lane & 15;

  __shared__ __align__(16) short Qs[128 * 64];
  __shared__ __align__(16) short Ks[64 * 64];
  __shared__ __align__(16) short VTs[64 * 64];
  __shared__ __align__(16) short Ps[128 * 64];

  {
    const int r0 = tid >> 3, seg = tid & 7;
#pragma unroll
    for (int i = 0; i < 4; ++i) {
      int r = r0 + i * 32;
      short8 v = *(const short8*)(Qp + (size_t)(b * Tq + qt * 128 + r) * qStride + h * 64 + seg * 8);
      *(short8*)&Qs[r * 64 + ((seg ^ (r & 7)) << 3)] = v;
    }
  }
  __syncthreads();

  short8 aq[2][2];
#pragma unroll
  for (int m = 0; m < 2; ++m)
#pragma unroll
    for (int ks = 0; ks < 2; ++ks) {
      int row = w * 32 + m * 16 + li;
      aq[m][ks] = *(const short8*)&Qs[row * 64 + (((ks * 4 + g) ^ (row & 7)) << 3)];
    }

  float m_reg[2][4], l_reg[2][4];
  f32x4 o[2][4];
#pragma unroll
  for (int m = 0; m < 2; ++m)
#pragma unroll
    for (int r = 0; r < 4; ++r) { m_reg[m][r] = -INFINITY; l_reg[m][r] = 0.f; }
#pragma unroll
  for (int m = 0; m < 2; ++m)
#pragma unroll
    for (int n = 0; n < 4; ++n) o[m][n] = (f32x4){0.f, 0.f, 0.f, 0.f};

  const int nkt = Tkv >> 6;
  const unsigned short* vt = VTg + (size_t)(b * NH_ + h) * 64 * Tkv;
  const int r0 = tid >> 3, seg = tid & 7;
  const int sr0 = r0, sr1 = r0 + 32;

  short8 kr0, kr1, vr0, vr1;
  kr0 = *(const short8*)(Kp + (size_t)(b * Tkv + sr0) * kStride + h * 64 + seg * 8);
  kr1 = *(const short8*)(Kp + (size_t)(b * Tkv + sr1) * kStride + h * 64 + seg * 8);
  vr0 = *(const short8*)(vt + (size_t)sr0 * Tkv + seg * 8);
  vr1 = *(const short8*)(vt + (size_t)sr1 * Tkv + seg * 8);

  for (int kt = 0; kt < nkt; ++kt) {
    __syncthreads();
    *(short8*)&Ks[sr0 * 64 + ((seg ^ (sr0 & 7)) << 3)] = kr0;
    *(short8*)&Ks[sr1 * 64 + ((seg ^ (sr1 & 7)) << 3)] = kr1;
    *(short8*)&VTs[sr0 * 64 + ((seg ^ (sr0 & 7)) << 3)] = vr0;
    *(short8*)&VTs[sr1 * 64 + ((seg ^ (sr1 & 7)) << 3)] = vr1;
    if (kt + 1 < nkt) {
      int kb = (kt + 1) * 64;
      kr0 = *(const short8*)(Kp + (size_t)(b * Tkv + kb + sr0) * kStride + h * 64 + seg * 8);
      kr1 = *(const short8*)(Kp + (size_t)(b * Tkv + kb + sr1) * kStride + h * 64 + seg * 8);
      vr0 = *(const short8*)(vt + (size_t)sr0 * Tkv + kb + seg * 8);
      vr1 = *(const short8*)(vt + (size_t)sr1 * Tkv + kb + seg * 8);
    }
    __syncthreads();

    f32x4 s[2][4];
    __builtin_amdgcn_s_setprio(1);
#pragma unroll
    for (int m = 0; m < 2; ++m)
#pragma unroll
      for (int n = 0; n < 4; ++n) {
        f32x4 acc = (f32x4){0.f, 0.f, 0.f, 0.f};
#pragma unroll
        for (int ks = 0; ks < 2; ++ks) {
          int key = n * 16 + li;
          short8 bk = *(const short8*)&Ks[key * 64 + (((ks * 4 + g) ^ (key & 7)) << 3)];
          acc = __builtin_amdgcn_mfma_f32_16x16x32_bf16(aq[m][ks], bk, acc, 0, 0, 0);
        }
        s[m][n] = acc * 0.125f;
      }
    __builtin_amdgcn_s_setprio(0);

    float alpha[2][4];
#pragma unroll
    for (int m = 0; m < 2; ++m)
#pragma unroll
      for (int r = 0; r < 4; ++r) {
        float pm = fmaxf(fmaxf(s[m][0][r], s[m][1][r]), fmaxf(s[m][2][r], s[m][3][r]));
#pragma unroll
        for (int off = 1; off < 16; off <<= 1) pm = fmaxf(pm, __shfl_xor(pm, off));
        float mn = fmaxf(m_reg[m][r], pm);
        alpha[m][r] = __expf(m_reg[m][r] - mn);
        float ls = 0.f;
        int row = w * 32 + m * 16 + g * 4 + r;
#pragma unroll
        for (int n = 0; n < 4; ++n) {
          float p = __expf(s[m][n][r] - mn);
          ls += p;
          int col = n * 16 + li;
          Ps[row * 64 + (col ^ ((row & 7) << 3))] = (short)f2bf(p);
        }
#pragma unroll
        for (int off = 1; off < 16; off <<= 1) ls += __shfl_xor(ls, off);
        l_reg[m][r] = l_reg[m][r] * alpha[m][r] + ls;
        m_reg[m][r] = mn;
      }

#pragma unroll
    for (int m = 0; m < 2; ++m) {
      f32x4 al = (f32x4){alpha[m][0], alpha[m][1], alpha[m][2], alpha[m][3]};
#pragma unroll
      for (int n = 0; n < 4; ++n) o[m][n] *= al;
    }
    short8 ap[2][2];
#pragma unroll
    for (int m = 0; m < 2; ++m)
#pragma unroll
      for (int ks = 0; ks < 2; ++ks) {
        int row = w * 32 + m * 16 + li;
        ap[m][ks] = *(const short8*)&Ps[row * 64 + (((ks * 4 + g) ^ (row & 7)) << 3)];
      }
    __builtin_amdgcn_s_setprio(1);
#pragma unroll
    for (int m = 0; m < 2; ++m)
#pragma unroll
      for (int n = 0; n < 4; ++n)
#pragma unroll
        for (int ks = 0; ks < 2; ++ks) {
          int d = n * 16 + li;
          short8 bv = *(const short8*)&VTs[d * 64 + (((ks * 4 + g) ^ (d & 7)) << 3)];
          o[m][n] = __builtin_amdgcn_mfma_f32_16x16x32_bf16(ap[m][ks], bv, o[m][n], 0, 0, 0);
        }
    __builtin_amdgcn_s_setprio(0);
  }

#pragma unroll
  for (int m = 0; m < 2; ++m)
#pragma unroll
    for (int n = 0; n < 4; ++n)
#pragma unroll
      for (int r = 0; r < 4; ++r) {
        float v = o[m][n][r] / l_reg[m][r];
        Op[(size_t)(b * Tq + qt * 128 + w * 32 + m * 16 + g * 4 + r) * 256 + h * 64 + n * 16 + li] = f2bf(v);
      }
}

// ---------------------------------------------------------------------------
// bf16 MFMA flash attention, CA variant: SH-aliased 32KB LDS (r10-verified),
// 4 blk/CU. CA footprint (K+V^T = 64KB/(b,h)) is L2-safe at high occupancy.
// ---------------------------------------------------------------------------
__global__ __launch_bounds__(256, 4) void attn_bf2_k(
    const unsigned short* __restrict__ Qp, int qStride,
    const unsigned short* __restrict__ Kp, int kStride,
    const unsigned short* __restrict__ VTg,
    unsigned short* __restrict__ Op, int Tq, int Tkv)
{
  int b, h, qt;
  {
    const int nqt = gridDim.x, nh = gridDim.y, nbh = gridDim.y * gridDim.z;
    if ((nbh & 7) == 0) {
      int linear = blockIdx.x + nqt * (blockIdx.y + gridDim.y * blockIdx.z);
      int xcd = linear & 7, idx = linear >> 3;
      int bh = xcd * (nbh >> 3) + idx / nqt;
      qt = idx - (idx / nqt) * nqt;
      h = bh % nh; b = bh / nh;
    } else { qt = blockIdx.x; h = blockIdx.y; b = blockIdx.z; }
  }
  const int tid = threadIdx.x;
  const int lane = tid & 63, w = tid >> 6;
  const int g = lane >> 4, li = lane & 15;

  __shared__ __align__(16) short SH[128 * 64];   // Q staging -> P tiles
  __shared__ __align__(16) short Ks[64 * 64];
  __shared__ __align__(16) short VTs[64 * 64];

  {
    const int r0 = tid >> 3, seg = tid & 7;
#pragma unroll
    for (int i = 0; i < 4; ++i) {
      int r = r0 + i * 32;
      short8 v = *(const short8*)(Qp + (size_t)(b * Tq + qt * 128 + r) * qStride + h * 64 + seg * 8);
      *(short8*)&SH[r * 64 + ((seg ^ (r & 7)) << 3)] = v;
    }
  }
  __syncthreads();

  short8 aq[2][2];
#pragma unroll
  for (int m = 0; m < 2; ++m)
#pragma unroll
    for (int ks = 0; ks < 2; ++ks) {
      int row = w * 32 + m * 16 + li;
      aq[m][ks] = *(const short8*)&SH[row * 64 + (((ks * 4 + g) ^ (row & 7)) << 3)];
    }

  float m_reg[2][4], l_reg[2][4];
  f32x4 o[2][4];
#pragma unroll
  for (int m = 0; m < 2; ++m)
#pragma unroll
    for (int r = 0; r < 4; ++r) { m_reg[m][r] = -INFINITY; l_reg[m][r] = 0.f; }
#pragma unroll
  for (int m = 0; m < 2; ++m)
#pragma unroll
    for (int n = 0; n < 4; ++n) o[m][n] = (f32x4){0.f, 0.f, 0.f, 0.f};

  const int nkt = Tkv >> 6;
  const unsigned short* vt = VTg + (size_t)(b * NH_ + h) * 64 * Tkv;
  const int r0 = tid >> 3, seg = tid & 7;
  const int sr0 = r0, sr1 = r0 + 32;

  short8 kr0, kr1, vr0, vr1;
  kr0 = *(const short8*)(Kp + (size_t)(b * Tkv + sr0) * kStride + h * 64 + seg * 8);
  kr1 = *(const short8*)(Kp + (size_t)(b * Tkv + sr1) * kStride + h * 64 + seg * 8);
  vr0 = *(const short8*)(vt + (size_t)sr0 * Tkv + seg * 8);
  vr1 = *(const short8*)(vt + (size_t)sr1 * Tkv + seg * 8);

  for (int kt = 0; kt < nkt; ++kt) {
    __syncthreads();
    *(short8*)&Ks[sr0 * 64 + ((seg ^ (sr0 & 7)) << 3)] = kr0;
    *(short8*)&Ks[sr1 * 64 + ((seg ^ (sr1 & 7)) << 3)] = kr1;
    *(short8*)&VTs[sr0 * 64 + ((seg ^ (sr0 & 7)) << 3)] = vr0;
    *(short8*)&VTs[sr1 * 64 + ((seg ^ (sr1 & 7)) << 3)] = vr1;
    if (kt + 1 < nkt) {
      int kb = (kt + 1) * 64;
      kr0 = *(const short8*)(Kp + (size_t)(b * Tkv + kb + sr0) * kStride + h * 64 + seg * 8);
      kr1 = *(const short8*)(Kp + (size_t)(b * Tkv + kb + sr1) * kStride + h * 64 + seg * 8);
      vr0 = *(const short8*)(vt + (size_t)sr0 * Tkv + kb + seg * 8);
      vr1 = *(const short8*)(vt + (size_t)sr1 * Tkv + kb + seg * 8);
    }
    __syncthreads();

    f32x4 s[2][4];
    __builtin_amdgcn_s_setprio(1);
#pragma unroll
    for (int m = 0; m < 2; ++m)
#pragma unroll
      for (int n = 0; n < 4; ++n) {
        f32x4 acc = (f32x4){0.f, 0.f, 0.f, 0.f};
#pragma unroll
        for (int ks = 0; ks < 2; ++ks) {
          int key = n * 16 + li;
          short8 bk = *(const short8*)&Ks[key * 64 + (((ks * 4 + g) ^ (key & 7)) << 3)];
          acc = __builtin_amdgcn_mfma_f32_16x16x32_bf16(aq[m][ks], bk, acc, 0, 0, 0);
        }
        s[m][n] = acc * 0.125f;
      }
    __builtin_amdgcn_s_setprio(0);

    float alpha[2][4];
#pragma unroll
    for (int m = 0; m < 2; ++m)
#pragma unroll
      for (int r = 0; r < 4; ++r) {
        float pm = fmaxf(fmaxf(s[m][0][r], s[m][1][r]), fmaxf(s[m][2][r], s[m][3][r]));
#pragma unroll
        for (int off = 1; off < 16; off <<= 1) pm = fmaxf(pm, __shfl_xor(pm, off));
        float mn = fmaxf(m_reg[m][r], pm);
        alpha[m][r] = __expf(m_reg[m][r] - mn);
        float ls = 0.f;
        int row = w * 32 + m * 16 + g * 4 + r;
#pragma unroll
        for (int n = 0; n < 4; ++n) {
          float p = __expf(s[m][n][r] - mn);
          ls += p;
          int col = n * 16 + li;
          SH[row * 64 + (col ^ ((row & 7) << 3))] = (short)f2bf(p);
        }
#pragma unroll
        for (int off = 1; off < 16; off <<= 1) ls += __shfl_xor(ls, off);
        l_reg[m][r] = l_reg[m][r] * alpha[m][r] + ls;
        m_reg[m][r] = mn;
      }

#pragma unroll
    for (int m = 0; m < 2; ++m) {
      f32x4 al = (f32x4){alpha[m][0], alpha[m][1], alpha[m][2], alpha[m][3]};
#pragma unroll
      for (int n = 0; n < 4; ++n) o[m][n] *= al;
    }
    short8 ap[2][2];
#pragma unroll
    for (int m = 0; m < 2; ++m)
#pragma unroll
      for (int ks = 0; ks < 2; ++ks) {
        int row = w * 32 + m * 16 + li;
        ap[m][ks] = *(const short8*)&SH[row * 64 + (((ks * 4 + g) ^ (row & 7)) << 3)];
      }
    __builtin_amdgcn_s_setprio(1);
#pragma unroll
    for (int m = 0; m < 2; ++m)
#pragma unroll
      for (int n = 0; n < 4; ++n)
#pragma unroll
        for (int ks = 0; ks < 2; ++ks) {
          int d = n * 16 + li;
          short8 bv = *(const short8*)&VTs[d * 64 + (((ks * 4 + g) ^ (d & 7)) << 3)];
          o[m][n] = __builtin_amdgcn_mfma_f32_16x16x32_bf16(ap[m][ks], bv, o[m][n], 0, 0, 0);
        }
    __builtin_amdgcn_s_setprio(0);
  }

#pragma unroll
  for (int m = 0; m < 2; ++m)
#pragma unroll
    for (int n = 0; n < 4; ++n)
#pragma unroll
      for (int r = 0; r < 4; ++r) {
        float v = o[m][n][r] / l_reg[m][r];
        Op[(size_t)(b * Tq + qt * 128 + w * 32 + m * 16 + g * 4 + r) * 256 + h * 64 + n * 16 + li] = f2bf(v);
      }
}

// LayerNorm f32 (encoder/vpred) — unchanged.
__global__ __launch_bounds__(256) void addln_k(
    const float* __restrict__ X, const float* __restrict__ R,
    const float* __restrict__ w, const float* __restrict__ bias,
    float* __restrict__ Out, int rows)
{
  int tid = threadIdx.x, wv = tid >> 6, ln = tid & 63;
  int row = blockIdx.x * 4 + wv;
  if (row >= rows) return;
  const float* xp = X + (size_t)row * 256;
  float v[4];
#pragma unroll
  for (int u = 0; u < 4; ++u) v[u] = xp[u * 64 + ln];
  if (R) {
    const float* rp = R + (size_t)row * 256;
#pragma unroll
    for (int u = 0; u < 4; ++u) v[u] += rp[u * 64 + ln];
  }
  float s = v[0] + v[1] + v[2] + v[3];
#pragma unroll
  for (int off = 1; off < 64; off <<= 1) s += __shfl_xor(s, off);
  float mean = s * (1.f / 256.f);
  float c[4], sq = 0.f;
#pragma unroll
  for (int u = 0; u < 4; ++u) { c[u] = v[u] - mean; sq += c[u] * c[u]; }
#pragma unroll
  for (int off = 1; off < 64; off <<= 1) sq += __shfl_xor(sq, off);
  float rs = 1.f / sqrtf(sq * (1.f / 256.f) + 1e-5f);
  float* op = Out + (size_t)row * 256;
#pragma unroll
  for (int u = 0; u < 4; ++u)
    op[u * 64 + ln] = c[u] * rs * w[u * 64 + ln] + bias[u * 64 + ln];
}

// Decoder LayerNorm: bf16 state + bf16 residual -> bf16 state (f32 math).
__global__ __launch_bounds__(256) void addlnb_k(
    unsigned short* __restrict__ Xbf, const unsigned short* __restrict__ Rbf,
    const float* __restrict__ w, const float* __restrict__ bias, int rows)
{
  int tid = threadIdx.x, wv = tid >> 6, ln = tid & 63;
  int row = blockIdx.x * 4 + wv;
  if (row >= rows) return;
  unsigned short* xp = Xbf + (size_t)row * 256;
  const unsigned short* rp = Rbf + (size_t)row * 256;
  float v[4];
#pragma unroll
  for (int u = 0; u < 4; ++u) v[u] = bf2f(xp[u * 64 + ln]) + bf2f(rp[u * 64 + ln]);
  float s = v[0] + v[1] + v[2] + v[3];
#pragma unroll
  for (int off = 1; off < 64; off <<= 1) s += __shfl_xor(s, off);
  float mean = s * (1.f / 256.f);
  float c[4], sq = 0.f;
#pragma unroll
  for (int u = 0; u < 4; ++u) { c[u] = v[u] - mean; sq += c[u] * c[u]; }
#pragma unroll
  for (int off = 1; off < 64; off <<= 1) sq += __shfl_xor(sq, off);
  float rs = 1.f / sqrtf(sq * (1.f / 256.f) + 1e-5f);
#pragma unroll
  for (int u = 0; u < 4; ++u) {
    float y = c[u] * rs * w[u * 64 + ln] + bias[u * 64 + ln];
    xp[u * 64 + ln] = f2bf(y);
  }
}

// Conv1d k=3 pad=1 — unchanged (r12 vectorized).
__global__ __launch_bounds__(256) void conv_k(
    const float* __restrict__ X, const float* __restrict__ Wt,
    const float* __restrict__ bias, float* __restrict__ Yo, int relu)
{
  const int b = blockIdx.z;
  const int o0 = blockIdx.y * 64, t0 = blockIdx.x * 64;
  const int tid = threadIdx.x, tx = tid & 15, ty = tid >> 4;
  __shared__ __align__(16) float xs[16][68];
  __shared__ __align__(16) float ws_s[64][48];
  float acc[4][4] = {{0.f,0.f,0.f,0.f},{0.f,0.f,0.f,0.f},{0.f,0.f,0.f,0.f},{0.f,0.f,0.f,0.f}};
  for (int i0 = 0; i0 < 256; i0 += 16) {
    for (int idx = tid; idx < 16 * 68; idx += 256) {
      int ic = idx / 68, tt = idx - ic * 68;
      int t = t0 + tt - 1;
      xs[ic][tt] = (tt < 66 && t >= 0 && t < 256)
                       ? X[((size_t)b * 256 + (i0 + ic)) * 256 + t] : 0.f;
    }
    for (int f4 = tid; f4 < 768; f4 += 256) {
      int oo = f4 / 12, seg = f4 - oo * 12;
      float4 v = *(const float4*)(Wt + (size_t)(o0 + oo) * 768 + i0 * 3 + seg * 4);
      *(float4*)&ws_s[oo][seg * 4] = v;
    }
    __syncthreads();
#pragma unroll
    for (int ic = 0; ic < 16; ++ic) {
      float4 xa = *(const float4*)&xs[ic][tx * 4];
      float4 xb = *(const float4*)&xs[ic][tx * 4 + 4];
      float xr[6] = {xa.x, xa.y, xa.z, xa.w, xb.x, xb.y};
#pragma unroll
      for (int i = 0; i < 4; ++i) {
        const float* wr = &ws_s[ty * 4 + i][ic * 3];
        float w0 = wr[0], w1 = wr[1], w2 = wr[2];
#pragma unroll
        for (int j = 0; j < 4; ++j)
          acc[i][j] += w0 * xr[j] + w1 * xr[j + 1] + w2 * xr[j + 2];
      }
    }
    __syncthreads();
  }
#pragma unroll
  for (int i = 0; i < 4; ++i) {
    int oo = o0 + ty * 4 + i;
    float bv = bias[oo];
#pragma unroll
    for (int j = 0; j < 4; ++j) {
      float v = acc[i][j] + bv;
      if (relu) v = fmaxf(v, 0.f);
      Yo[((size_t)b * 256 + oo) * 256 + t0 + tx * 4 + j] = v;
    }
  }
}

__global__ void transp_k(const float* __restrict__ In, float* __restrict__ Out)
{
  int b = blockIdx.z, t0 = blockIdx.x * 32, d0 = blockIdx.y * 32;
  __shared__ float tile[32][33];
  int tx = threadIdx.x, ty = threadIdx.y;
#pragma unroll
  for (int q = 0; q < 4; ++q)
    tile[ty + q * 8][tx] = In[((size_t)b * 256 + t0 + ty + q * 8) * 256 + d0 + tx];
  __syncthreads();
#pragma unroll
  for (int q = 0; q < 4; ++q)
    Out[((size_t)b * 256 + d0 + ty + q * 8) * 256 + t0 + tx] = tile[tx][ty + q * 8];
}

__global__ __launch_bounds__(256) void rowdot_k(
    const float* __restrict__ H, const float* __restrict__ lw,
    const float* __restrict__ lb, float* __restrict__ of32,
    float* __restrict__ oout, int rows)
{
  int tid = threadIdx.x, wv = tid >> 6, ln = tid & 63;
  int row = blockIdx.x * 4 + wv;
  if (row >= rows) return;
  const float* hp = H + (size_t)row * 256;
  float s = 0.f;
#pragma unroll
  for (int u = 0; u < 4; ++u) s += hp[u * 64 + ln] * lw[u * 64 + ln];
#pragma unroll
  for (int off = 1; off < 64; off <<= 1) s += __shfl_xor(s, off);
  if (ln == 0) {
    float v = s + lb[0];
    of32[row] = v;
    oout[row] = v;
  }
}

__global__ void maxlen_k(const float* __restrict__ dur, int* __restrict__ ml)
{
  __shared__ float rnds[32];
  int tid = threadIdx.x, wv = tid >> 6, ln = tid & 63;
  for (int b = wv; b < 32; b += 4) {
    const float* dp = dur + (size_t)b * 256;
    float s = dp[ln] + dp[64 + ln] + dp[128 + ln] + dp[192 + ln];
#pragma unroll
    for (int off = 1; off < 64; off <<= 1) s += __shfl_xor(s, off);
    if (ln == 0) rnds[b] = rintf(s);
  }
  __syncthreads();
  if (tid == 0) {
    float m = rnds[0];
    for (int b = 1; b < 32; ++b) m = fmaxf(m, rnds[b]);
    int v = (int)m;
    v = v < 0 ? 0 : (v > MAXBUF_ ? MAXBUF_ : v);
    *ml = v;
  }
}

__global__ void reg_k(const float* __restrict__ dur, const int* __restrict__ lens,
                      const int* __restrict__ ml, int* __restrict__ tok)
{
  int b = blockIdx.x;
  __shared__ float sdur[256];
  __shared__ int ends[256];
  int tid = threadIdx.x;
  sdur[tid] = dur[(size_t)b * 256 + tid];
  __syncthreads();
  if (tid == 0) {
    int maxlen = *ml, len = lens[b], pos = 0;
    for (int t = 0; t < 256; ++t) {
      int d = (int)rintf(sdur[t]);
      bool ok = (t < len) && (d > 0) && (pos + d <= maxlen);
      if (ok) pos += d;
      ends[t] = pos;
    }
  }
  __syncthreads();
  int total = ends[255];
  for (int f = tid; f < MAXBUF_; f += 256) {
    int lo = 0, hi = 256;
    while (lo < hi) { int mid = (lo + hi) >> 1; if (ends[mid] <= f) lo = mid + 1; else hi = mid; }
    int tc = lo > 255 ? 255 : lo;
    tok[(size_t)b * MAXBUF_ + f] = (f < total) ? tc : -1;
  }
}

// Y[b,f,:] = tok>=0 ? bf16(enc[b,tok,:]) : 0  (bf16 state)
__global__ void gatherb_k(const float* __restrict__ enc, const int* __restrict__ tok,
                          unsigned short* __restrict__ Ybf)
{
  int rf = blockIdx.x;
  int b = rf >> 10;
  int t = tok[rf];
  unsigned short* dst = Ybf + (size_t)rf * 256;
  int ln = threadIdx.x;
  if (t >= 0) {
    float4 v = ((const float4*)(enc + ((size_t)b * 256 + t) * 256))[ln];
    unsigned short o[4] = {f2bf(v.x), f2bf(v.y), f2bf(v.z), f2bf(v.w)};
    *(ushort4*)(dst + ln * 4) = *(ushort4*)o;
  } else {
    unsigned short o[4] = {0, 0, 0, 0};
    *(ushort4*)(dst + ln * 4) = *(ushort4*)o;
  }
}

// MEL (B*1024, 80) -> out (B, 80, 1024) via LDS tile transpose
__global__ __launch_bounds__(256) void meltr_k(
    const float* __restrict__ MEL, float* __restrict__ out)
{
  int b = blockIdx.z, m0 = blockIdx.y * 16, f0 = blockIdx.x * 64;
  __shared__ float t[16][65];
  int tid = threadIdx.x;
  {
    int f_i = tid >> 4, m_i = tid & 15;
#pragma unroll
    for (int q = 0; q < 4; ++q)
      t[m_i][f_i + q * 16] = MEL[((size_t)b * 1024 + f0 + f_i + q * 16) * 80 + m0 + m_i];
  }
  __syncthreads();
  {
    int f = tid & 63, my = tid >> 6;
#pragma unroll
    for (int q = 0; q < 4; ++q) {
      int m = my * 4 + q;
      out[((size_t)b * NMEL_ + m0 + m) * MAXBUF_ + f0 + f] = t[m][f];
    }
  }
}

// ============================================================================
extern "C" void kernel_launch(void* const* d_in, const int* in_sizes, int n_in,
                              void* d_out, int out_size, void* d_ws, size_t ws_size,
                              hipStream_t stream)
{
  (void)in_sizes; (void)n_in; (void)out_size;

  const float* te   = (const float*)d_in[0];
  const int*   lens = (const int*)d_in[1];
  const float* e_qkv_w = (const float*)d_in[2];
  const float* e_qkv_b = (const float*)d_in[3];
  const float* e_out_w = (const float*)d_in[4];
  const float* e_out_b = (const float*)d_in[5];
  const float* e_ln1_w = (const float*)d_in[6];
  const float* e_ln1_b = (const float*)d_in[7];
  const float* e_ff1_w = (const float*)d_in[8];
  const float* e_ff1_b = (const float*)d_in[9];
  const float* e_ff2_w = (const float*)d_in[10];
  const float* e_ff2_b = (const float*)d_in[11];
  const float* e_ln2_w = (const float*)d_in[12];
  const float* e_ln2_b = (const float*)d_in[13];
  const float* c1w = (const float*)d_in[14];
  const float* c1b = (const float*)d_in[15];
  const float* l1w = (const float*)d_in[16];
  const float* l1b = (const float*)d_in[17];
  const float* c2w = (const float*)d_in[18];
  const float* c2b = (const float*)d_in[19];
  const float* l2w = (const float*)d_in[20];
  const float* l2b = (const float*)d_in[21];
  const float* linw = (const float*)d_in[22];
  const float* linb = (const float*)d_in[23];
  const float* d_sa_qkv_w = (const float*)d_in[24];
  const float* d_sa_qkv_b = (const float*)d_in[25];
  const float* d_sa_out_w = (const float*)d_in[26];
  const float* d_sa_out_b = (const float*)d_in[27];
  const float* d_ca_qkv_w = (const float*)d_in[28];
  const float* d_ca_qkv_b = (const float*)d_in[29];
  const float* d_ca_out_w = (const float*)d_in[30];
  const float* d_ca_out_b = (const float*)d_in[31];
  const float* d_ln1_w = (const float*)d_in[32];
  const float* d_ln1_b = (const float*)d_in[33];
  const float* d_ln2_w = (const float*)d_in[34];
  const float* d_ln2_b = (const float*)d_in[35];
  const float* d_ln3_w = (const float*)d_in[36];
  const float* d_ln3_b = (const float*)d_in[37];
  const float* d_ff1_w = (const float*)d_in[38];
  const float* d_ff1_b = (const float*)d_in[39];
  const float* d_ff2_w = (const float*)d_in[40];
  const float* d_ff2_b = (const float*)d_in[41];
  const float* melw = (const float*)d_in[42];
  const float* melb = (const float*)d_in[43];
  float* out = (float*)d_out;   // f32: mel | duration | pitch | energy

  // ---- arena ----
  char* p = (char*)d_ws;
  float* Y   = (float*)p;            p += 8388608ull * 4;    // split-K partials / vpred scratch
  float* ENC = (float*)p;            p += 2097152ull * 4;
  unsigned short* ENCbf = (unsigned short*)p; p += 2097152ull * 2;
  unsigned short* Wsaqkv = (unsigned short*)p; p += 786432ull * 2;
  unsigned short* Wsaout = (unsigned short*)p; p += 262144ull * 2;
  unsigned short* Wcaqkv = (unsigned short*)p; p += 786432ull * 2;
  unsigned short* Wcaout = (unsigned short*)p; p += 262144ull * 2;
  unsigned short* Wff1   = (unsigned short*)p; p += 1048576ull * 2;
  unsigned short* Wff2   = (unsigned short*)p; p += 1048576ull * 2;
  float* DUR = (float*)p;            p += 24576ull * 4;
  int* TOK   = (int*)p;              p += 32768ull * 4;
  int* MAXL  = (int*)p;              p += 4096;
  size_t fixed_b = (size_t)(p - (char*)d_ws);

  int grp = 1;
  {
    const int cand[6] = {32, 16, 8, 4, 2, 1};
    for (int c = 0; c < 6; ++c) {
      if (fixed_b + (size_t)cand[c] * 1835008ull * 2 <= ws_size) { grp = cand[c]; break; }
    }
  }
  unsigned short* REG = (unsigned short*)p;
  unsigned short* Ybf   = REG;
  unsigned short* ADDbf = REG + (size_t)grp * 262144;
  unsigned short* AObf  = REG + (size_t)grp * 524288;
  unsigned short* UN    = REG + (size_t)grp * 786432;
  unsigned short* VTb   = REG + (size_t)grp * 1572864;
  int grp_e = grp * 2 > 32 ? 32 : grp * 2;
  float* P0e = (float*)REG;
  float* P1e = P0e + (size_t)grp_e * 262144;
  float* P2e = P1e + (size_t)grp_e * 65536;
  float* ENCT = Y;
  float* H1   = Y + 2097152;
  float* H2   = Y + 4194304;
  float* MEL  = ENC;

  auto gemm2s = [&](const float* A, const float* W, const float* bias, float* C,
                    int M, int N, int K, int S, int epi) {
    int kChunk = K / S;
    gemm2p_k<<<dim3(M / 128, N / 128, S), dim3(256), 0, stream>>>(
        A, W, C, Y, M, N, kChunk, K);
    size_t MN = (size_t)M * N;
    rsum_k<<<dim3((unsigned)(MN / 1024)), dim3(256), 0, stream>>>(
        C, Y, bias, S - 1, N, MN, epi);
  };
  auto gemm_bf = [&](const unsigned short* A, const unsigned short* W, const float* bias,
                     unsigned short* C, int M, int N, int K, int epi) {
    dim3 g(M / 128, N / 128);
    gemm_bf_k<<<g, dim3(256), 0, stream>>>(A, W, bias, C, M, N, K, epi);
  };
  auto addln = [&](const float* X, const float* R, const float* w, const float* b,
                   float* O, int rows) {
    addln_k<<<dim3((rows + 3) / 4), dim3(256), 0, stream>>>(X, R, w, b, O, rows);
  };
  auto addlnb = [&](unsigned short* Xbf, const unsigned short* Rbf, const float* w,
                    const float* b, int rows) {
    addlnb_k<<<dim3((rows + 3) / 4), dim3(256), 0, stream>>>(Xbf, Rbf, w, b, rows);
  };
  auto cvt = [&](const float* in, unsigned short* o, int n) {
    cvt_k<<<dim3(n / 1024), dim3(256), 0, stream>>>(in, o, n);
  };

  // ---- convert decoder weights to bf16 (once) ----
  cvt(d_sa_qkv_w, Wsaqkv, 786432);
  cvt(d_sa_out_w, Wsaout, 262144);
  cvt(d_ca_qkv_w, Wcaqkv, 786432);
  cvt(d_ca_out_w, Wcaout, 262144);
  cvt(d_ff1_w, Wff1, 1048576);
  cvt(d_ff2_w, Wff2, 1048576);

  // ================= encoder (fp32; split-K on starved GEMMs) =============
  for (int i = 0; i < 4; ++i) {
    for (int g0 = 0; g0 < B_; g0 += grp_e) {
      int rows = grp_e * T_;
      const size_t off = (size_t)g0 * T_ * D_;
      const float* xin = (i == 0) ? te + off : ENC + off;
      gemm2s(xin, e_qkv_w + (size_t)i * 196608, e_qkv_b + i * 768, P0e, rows, 768, 256, 2, 0);
      attn_k<<<dim3(T_ / 64, NH_, grp_e), dim3(256), 0, stream>>>(
          P0e, 768, P0e + 256, 768, P0e + 512, 768, P1e, T_, T_, lens + g0);
      gemm2s(P1e, e_out_w + (size_t)i * 65536, e_out_b + i * 256, P2e, rows, 256, 256, 4, 0);
      addln(xin, P2e, e_ln1_w + i * 256, e_ln1_b + i * 256, ENC + off, rows);
      gemm2s(ENC + off, e_ff1_w + (size_t)i * 262144, e_ff1_b + i * 1024, P0e, rows, 1024, 256, 2, 1);
      gemm2s(P0e, e_ff2_w + (size_t)i * 262144, e_ff2_b + i * 256, P2e, rows, 256, 1024, 4, 0);
      addln(ENC + off, P2e, e_ln2_w + i * 256, e_ln2_b + i * 256, ENC + off, rows);
    }
  }
  cvt(ENC, ENCbf, 2097152);

  // ================= variance predictors (fp32) =================
  transp_k<<<dim3(8, 8, B_), dim3(32, 8), 0, stream>>>(ENC, ENCT);
  for (int j = 0; j < 3; ++j) {
    conv_k<<<dim3(4, 4, B_), dim3(256), 0, stream>>>(
        ENCT, c1w + (size_t)j * 196608, c1b + j * 256, H1, 1);
    addln(H1, nullptr, l1w + j * 256, l1b + j * 256, H1, B_ * T_);
    conv_k<<<dim3(4, 4, B_), dim3(256), 0, stream>>>(
        H1, c2w + (size_t)j * 196608, c2b + j * 256, H2, 1);
    addln(H2, nullptr, l2w + j * 256, l2b + j * 256, H2, B_ * T_);
    rowdot_k<<<dim3(B_ * T_ / 4), dim3(256), 0, stream>>>(
        H2, linw + j * 256, linb + j, DUR + (size_t)j * 8192,
        out + 2621440 + (size_t)j * 8192, B_ * T_);
  }

  // ================= length regulator =================
  maxlen_k<<<dim3(1), dim3(256), 0, stream>>>(DUR, MAXL);
  reg_k<<<dim3(B_), dim3(256), 0, stream>>>(DUR, lens, MAXL, TOK);
  gatherb_k<<<dim3(B_ * MAXBUF_), dim3(64), 0, stream>>>(ENC, TOK, Ybf);

  // ================= decoder (bf16 MFMA; bf16 residual state) =============
  for (int i = 0; i < 4; ++i) {
    for (int g0 = 0; g0 < B_; g0 += grp) {
      int rows = grp * MAXBUF_;
      // self-attention (2 blk/CU L2-safe variant)
      gemm_bf(Ybf, Wsaqkv + (size_t)i * 196608, d_sa_qkv_b + i * 768, UN, rows, 768, 256, 0);
      trv_k<<<dim3(MAXBUF_ / 64, NH_, grp), dim3(256), 0, stream>>>(UN + 512, 768, VTb, MAXBUF_);
      attn_bf_k<<<dim3(MAXBUF_ / 128, NH_, grp), dim3(256), 0, stream>>>(
          UN, 768, UN + 256, 768, VTb, AObf, MAXBUF_, MAXBUF_);
      gemm_bf(AObf, Wsaout + (size_t)i * 65536, d_sa_out_b + i * 256, ADDbf, rows, 256, 256, 0);
      addlnb(Ybf, ADDbf, d_ln1_w + i * 256, d_ln1_b + i * 256, rows);
      // cross-attention (4 blk/CU aliased variant; tiny K/V footprint)
      gemm_bf(Ybf, Wcaqkv + (size_t)i * 196608, d_ca_qkv_b + i * 768, UN, rows, 256, 256, 0);
      gemm_bf(ENCbf + (size_t)g0 * 65536, Wcaqkv + (size_t)i * 196608 + 65536,
              d_ca_qkv_b + i * 768 + 256, UN + (size_t)grp * 262144, grp * T_, 512, 256, 0);
      trv_k<<<dim3(T_ / 64, NH_, grp), dim3(256), 0, stream>>>(
          UN + (size_t)grp * 262144 + 256, 512, VTb, T_);
      attn_bf2_k<<<dim3(MAXBUF_ / 128, NH_, grp), dim3(256), 0, stream>>>(
          UN, 256, UN + (size_t)grp * 262144, 512, VTb, AObf, MAXBUF_, T_);
      gemm_bf(AObf, Wcaout + (size_t)i * 65536, d_ca_out_b + i * 256, ADDbf, rows, 256, 256, 0);
      addlnb(Ybf, ADDbf, d_ln2_w + i * 256, d_ln2_b + i * 256, rows);
      // feed-forward
      gemm_bf(Ybf, Wff1 + (size_t)i * 262144, d_ff1_b + i * 1024, UN, rows, 1024, 256, 1);
      gemm_bf(UN, Wff2 + (size_t)i * 262144, d_ff2_b + i * 256, ADDbf, rows, 256, 1024, 0);
      addlnb(Ybf, ADDbf, d_ln3_w + i * 256, d_ln3_b + i * 256, rows);
    }
  }

  // ================= mel head: bf16-A gemm + transpose =================
  gemm_kb_k<<<dim3((B_ * MAXBUF_ + 63) / 64, (NMEL_ + 63) / 64), dim3(256), 0, stream>>>(
      Ybf, melw, melb, MEL, B_ * MAXBUF_, NMEL_, 256);
  meltr_k<<<dim3(16, 5, B_), dim3(256), 0, stream>>>(MEL, out);
}

// Round 15
// 3090.655 us; speedup vs baseline: 1.1000x; 1.1000x over previous
//
#include <hip/hip_runtime.h>
#include <hip/hip_bf16.h>
#include <cstdint>
#include <cstddef>

// ============================================================================
// FastSpeech2 forward on MI355X. Round 15: revert CA to the 2-blk/CU kernel.
//  r14 counters: attn_bf2_k (CA @ 4 blk/CU) FETCH 151MB, 160us/dispatch.
//  Root cause (3rd confirmation of the occupancy<->L2 law): aggregate working
//  set of 128 concurrent blocks/XCD (~10MB) >> 4MB L2 -> thrash. Per-(b,h)
//  footprint analysis was the wrong unit. CA back to attn_bf_k (2 blk/CU).
//  Keep r14's attn_k 68-float row pad (principled conflict fix).
//  Everything else identical to r13/r14 (passed, absmax 0.0117).
// ============================================================================

#define B_ 32
#define T_ 256
#define D_ 256
#define NH_ 4
#define FF_ 1024
#define MAXBUF_ 1024
#define NMEL_ 80

typedef __attribute__((ext_vector_type(8))) short short8;
typedef __attribute__((ext_vector_type(4))) float f32x4;

__device__ __forceinline__ unsigned short f2bf(float x) {
  unsigned int u = __float_as_uint(x);
  return (unsigned short)((u + 0x7fffu + ((u >> 16) & 1u)) >> 16);
}
__device__ __forceinline__ float bf2f(unsigned short h) {
  return __uint_as_float(((unsigned int)h) << 16);
}

#define GLD16(g, s)                                                         \
  __builtin_amdgcn_global_load_lds(                                         \
      (__attribute__((address_space(1))) void*)(g),                         \
      (__attribute__((address_space(3))) void*)(s), 16, 0, 0)

// f32 -> bf16 bulk convert (n % 1024 == 0)
__global__ void cvt_k(const float* __restrict__ in, unsigned short* __restrict__ out, int n)
{
  int i = (blockIdx.x * 256 + threadIdx.x) * 4;
  if (i >= n) return;
  float4 v = *(const float4*)(in + i);
  unsigned short o[4] = {f2bf(v.x), f2bf(v.y), f2bf(v.z), f2bf(v.w)};
  *(ushort4*)(out + i) = *(ushort4*)o;
}

// ---------------------------------------------------------------------------
// Mel-head GEMM: A is bf16, W/bias f32, f32 accumulate/output. 64x64 tile.
// ---------------------------------------------------------------------------
__global__ __launch_bounds__(256) void gemm_kb_k(
    const unsigned short* __restrict__ A, const float* __restrict__ W,
    const float* __restrict__ bias, float* __restrict__ C,
    int M, int N, int K)
{
  __shared__ float As[16][64];
  __shared__ float Ws[16][64];
  const int tid = threadIdx.x;
  const int tx = tid & 15, ty = tid >> 4;
  const int bm = blockIdx.x * 64, bn = blockIdx.y * 64;
  const int lm = tid & 63, lk = tid >> 6;
  float acc[4][4] = {{0.f,0.f,0.f,0.f},{0.f,0.f,0.f,0.f},{0.f,0.f,0.f,0.f},{0.f,0.f,0.f,0.f}};
  const bool aok = (bm + lm) < M;
  const bool wok = (bn + lm) < N;
  const unsigned short* Ap = A + (size_t)(bm + lm) * K + lk * 4;
  const float* Wp = W + (size_t)(bn + lm) * K + lk * 4;
  for (int k0 = 0; k0 < K; k0 += 16) {
    float4 av = make_float4(0.f, 0.f, 0.f, 0.f);
    float4 wv = make_float4(0.f, 0.f, 0.f, 0.f);
    if (aok) {
      ushort4 au = *(const ushort4*)(Ap + k0);
      av.x = bf2f(au.x); av.y = bf2f(au.y); av.z = bf2f(au.z); av.w = bf2f(au.w);
    }
    if (wok) wv = *(const float4*)(Wp + k0);
    As[lk*4+0][lm] = av.x; As[lk*4+1][lm] = av.y; As[lk*4+2][lm] = av.z; As[lk*4+3][lm] = av.w;
    Ws[lk*4+0][lm] = wv.x; Ws[lk*4+1][lm] = wv.y; Ws[lk*4+2][lm] = wv.z; Ws[lk*4+3][lm] = wv.w;
    __syncthreads();
#pragma unroll
    for (int kk = 0; kk < 16; ++kk) {
      float4 a4 = *(const float4*)&As[kk][ty * 4];
      float4 b4 = *(const float4*)&Ws[kk][tx * 4];
      float aa[4] = {a4.x, a4.y, a4.z, a4.w};
      float bb[4] = {b4.x, b4.y, b4.z, b4.w};
#pragma unroll
      for (int i = 0; i < 4; ++i)
#pragma unroll
        for (int j = 0; j < 4; ++j)
          acc[i][j] += aa[i] * bb[j];
    }
    __syncthreads();
  }
#pragma unroll
  for (int i = 0; i < 4; ++i) {
    int gm = bm + ty * 4 + i;
    if (gm >= M) continue;
#pragma unroll
    for (int j = 0; j < 4; ++j) {
      int gn = bn + tx * 4 + j;
      if (gn >= N) continue;
      C[(size_t)gm * N + gn] = acc[i][j] + bias[gn];
    }
  }
}

// ---------------------------------------------------------------------------
// Split-K partial GEMM + fixed-order reduce (optional gelu) — unchanged.
// ---------------------------------------------------------------------------
__global__ __launch_bounds__(256, 2) void gemm2p_k(
    const float* __restrict__ A, const float* __restrict__ W,
    float* __restrict__ Dst, float* __restrict__ Palt,
    int M, int N, int kChunk, int Ktot)
{
  __shared__ float As[16][128];
  __shared__ float Bs[16][128];
  const int tid = threadIdx.x;
  const int tx = tid & 15, ty = tid >> 4;
  const int bm = blockIdx.x * 128, bn = blockIdx.y * 128;
  const int z = blockIdx.z;
  const int r = tid & 127, ks = (tid >> 7) * 8;
  f32x4 acc[8][2];
#pragma unroll
  for (int i = 0; i < 8; ++i) {
    acc[i][0] = (f32x4){0.f, 0.f, 0.f, 0.f};
    acc[i][1] = (f32x4){0.f, 0.f, 0.f, 0.f};
  }
  const float* Ap = A + (size_t)(bm + r) * Ktot + z * kChunk + ks;
  const float* Wp = W + (size_t)(bn + r) * Ktot + z * kChunk + ks;
  for (int k0 = 0; k0 < kChunk; k0 += 16) {
    float4 a0 = *(const float4*)(Ap + k0);
    float4 a1 = *(const float4*)(Ap + k0 + 4);
    float4 w0 = *(const float4*)(Wp + k0);
    float4 w1 = *(const float4*)(Wp + k0 + 4);
    __syncthreads();
    As[ks+0][r] = a0.x; As[ks+1][r] = a0.y; As[ks+2][r] = a0.z; As[ks+3][r] = a0.w;
    As[ks+4][r] = a1.x; As[ks+5][r] = a1.y; As[ks+6][r] = a1.z; As[ks+7][r] = a1.w;
    Bs[ks+0][r] = w0.x; Bs[ks+1][r] = w0.y; Bs[ks+2][r] = w0.z; Bs[ks+3][r] = w0.w;
    Bs[ks+4][r] = w1.x; Bs[ks+5][r] = w1.y; Bs[ks+6][r] = w1.z; Bs[ks+7][r] = w1.w;
    __syncthreads();
#pragma unroll
    for (int kk = 0; kk < 16; ++kk) {
      f32x4 bA = *(const f32x4*)&Bs[kk][tx * 4];
      f32x4 bB = *(const f32x4*)&Bs[kk][tx * 4 + 64];
      float4 aA = *(const float4*)&As[kk][ty * 4];
      float4 aB = *(const float4*)&As[kk][ty * 4 + 64];
      float av[8] = {aA.x, aA.y, aA.z, aA.w, aB.x, aB.y, aB.z, aB.w};
#pragma unroll
      for (int i = 0; i < 8; ++i) {
        acc[i][0] += bA * av[i];
        acc[i][1] += bB * av[i];
      }
    }
  }
  float* Out = (z == 0) ? Dst : (Palt + (size_t)(z - 1) * ((size_t)M * N));
#pragma unroll
  for (int i = 0; i < 8; ++i) {
    int gm = bm + (i >> 2) * 64 + ty * 4 + (i & 3);
#pragma unroll
    for (int half = 0; half < 2; ++half) {
      int gn = bn + half * 64 + tx * 4;
      float4 o;
      o.x = acc[i][half][0]; o.y = acc[i][half][1];
      o.z = acc[i][half][2]; o.w = acc[i][half][3];
      *(float4*)(Out + (size_t)gm * N + gn) = o;
    }
  }
}

__global__ __launch_bounds__(256) void rsum_k(
    float* __restrict__ C, const float* __restrict__ Palt,
    const float* __restrict__ bias, int Sm1, int N, size_t MN, int epi)
{
  size_t i = ((size_t)blockIdx.x * 256 + threadIdx.x) * 4;
  if (i >= MN) return;
  float4 a = *(const float4*)(C + i);
  for (int s = 0; s < Sm1; ++s) {
    float4 b = *(const float4*)(Palt + (size_t)s * MN + i);
    a.x += b.x; a.y += b.y; a.z += b.z; a.w += b.w;
  }
  int col = (int)(i % (size_t)N);
  a.x += bias[col + 0]; a.y += bias[col + 1];
  a.z += bias[col + 2]; a.w += bias[col + 3];
  if (epi == 1) {
    a.x = 0.5f * a.x * (1.0f + erff(a.x * 0.70710678118654752f));
    a.y = 0.5f * a.y * (1.0f + erff(a.y * 0.70710678118654752f));
    a.z = 0.5f * a.z * (1.0f + erff(a.z * 0.70710678118654752f));
    a.w = 0.5f * a.w * (1.0f + erff(a.w * 0.70710678118654752f));
  }
  *(float4*)(C + i) = a;
}

// ---------------------------------------------------------------------------
// fp32 flash attention (encoder; duration path). 68-float rows (r14 pad fix).
// ---------------------------------------------------------------------------
__global__ __launch_bounds__(256) void attn_k(
    const float* __restrict__ Qp, int qStride,
    const float* __restrict__ Kp, int kStride,
    const float* __restrict__ Vp, int vStride,
    float* __restrict__ Op, int Tq, int Tkv,
    const int* __restrict__ lengths)
{
  const int b = blockIdx.z, h = blockIdx.y, qt = blockIdx.x;
  const int tid = threadIdx.x;
  const int tx = tid & 15, ty = tid >> 4;
  const int lr = tid & 63, lq = tid >> 6;

  __shared__ __align__(16) float Qs[64][68];
  __shared__ __align__(16) float KT[64][68];
  __shared__ float Sm[64][65];

  {
    const float* q = Qp + (size_t)(b * Tq + qt * 64 + lr) * qStride + h * 64 + lq * 16;
    float4 v0 = ((const float4*)q)[0];
    float4 v1 = ((const float4*)q)[1];
    float4 v2 = ((const float4*)q)[2];
    float4 v3 = ((const float4*)q)[3];
    *(float4*)&Qs[lr][lq*16 + 0]  = v0;
    *(float4*)&Qs[lr][lq*16 + 4]  = v1;
    *(float4*)&Qs[lr][lq*16 + 8]  = v2;
    *(float4*)&Qs[lr][lq*16 + 12] = v3;
  }

  float m_reg[4], l_reg[4], o[4][4];
#pragma unroll
  for (int i = 0; i < 4; ++i) {
    m_reg[i] = -INFINITY; l_reg[i] = 0.f;
#pragma unroll
    for (int j = 0; j < 4; ++j) o[i][j] = 0.f;
  }

  const int len_b = lengths ? lengths[b] : 0x7fffffff;
  const int nkt = Tkv >> 6;

  float4 kreg[4], vreg[4];
  {
    const float* kp = Kp + (size_t)(b * Tkv + lr) * kStride + h * 64 + lq * 16;
    kreg[0] = ((const float4*)kp)[0]; kreg[1] = ((const float4*)kp)[1];
    kreg[2] = ((const float4*)kp)[2]; kreg[3] = ((const float4*)kp)[3];
    const float* vp = Vp + (size_t)(b * Tkv + lr) * vStride + h * 64 + lq * 16;
    vreg[0] = ((const float4*)vp)[0]; vreg[1] = ((const float4*)vp)[1];
    vreg[2] = ((const float4*)vp)[2]; vreg[3] = ((const float4*)vp)[3];
  }

  for (int kt = 0; kt < nkt; ++kt) {
    __syncthreads();
    {
#pragma unroll
      for (int u = 0; u < 4; ++u) {
        KT[lq*16 + u*4 + 0][lr] = kreg[u].x;
        KT[lq*16 + u*4 + 1][lr] = kreg[u].y;
        KT[lq*16 + u*4 + 2][lr] = kreg[u].z;
        KT[lq*16 + u*4 + 3][lr] = kreg[u].w;
      }
    }
    if (kt + 1 < nkt) {
      const float* kp = Kp + (size_t)(b * Tkv + (kt + 1) * 64 + lr) * kStride + h * 64 + lq * 16;
      kreg[0] = ((const float4*)kp)[0]; kreg[1] = ((const float4*)kp)[1];
      kreg[2] = ((const float4*)kp)[2]; kreg[3] = ((const float4*)kp)[3];
    }
    __syncthreads();

    float s[4][4] = {{0.f,0.f,0.f,0.f},{0.f,0.f,0.f,0.f},{0.f,0.f,0.f,0.f},{0.f,0.f,0.f,0.f}};
#pragma unroll
    for (int d4 = 0; d4 < 16; ++d4) {
      float4 qv[4], kv[4];
#pragma unroll
      for (int i = 0; i < 4; ++i) qv[i] = *(const float4*)&Qs[ty*4 + i][d4*4];
#pragma unroll
      for (int dd = 0; dd < 4; ++dd) kv[dd] = *(const float4*)&KT[d4*4 + dd][tx*4];
#pragma unroll
      for (int i = 0; i < 4; ++i) {
        s[i][0] += qv[i].x*kv[0].x + qv[i].y*kv[1].x + qv[i].z*kv[2].x + qv[i].w*kv[3].x;
        s[i][1] += qv[i].x*kv[0].y + qv[i].y*kv[1].y + qv[i].z*kv[2].y + qv[i].w*kv[3].y;
        s[i][2] += qv[i].x*kv[0].z + qv[i].y*kv[1].z + qv[i].z*kv[2].z + qv[i].w*kv[3].z;
        s[i][3] += qv[i].x*kv[0].w + qv[i].y*kv[1].w + qv[i].z*kv[2].w + qv[i].w*kv[3].w;
      }
    }

    float alpha[4];
#pragma unroll
    for (int i = 0; i < 4; ++i) {
      float pm = -INFINITY;
#pragma unroll
      for (int j = 0; j < 4; ++j) {
        int kg = kt * 64 + tx * 4 + j;
        float v = s[i][j] * 0.125f;
        if (kg >= len_b) v = -1e9f;
        s[i][j] = v;
        pm = fmaxf(pm, v);
      }
#pragma unroll
      for (int off = 1; off < 16; off <<= 1) pm = fmaxf(pm, __shfl_xor(pm, off));
      float mn = fmaxf(m_reg[i], pm);
      alpha[i] = expf(m_reg[i] - mn);
      float ls = 0.f;
#pragma unroll
      for (int j = 0; j < 4; ++j) {
        float p = expf(s[i][j] - mn);
        Sm[ty*4 + i][tx*4 + j] = p;
        ls += p;
      }
#pragma unroll
      for (int off = 1; off < 16; off <<= 1) ls += __shfl_xor(ls, off);
      l_reg[i] = l_reg[i] * alpha[i] + ls;
      m_reg[i] = mn;
    }
    __syncthreads();

    {
      *(float4*)&KT[lr][lq*16 + 0]  = vreg[0];
      *(float4*)&KT[lr][lq*16 + 4]  = vreg[1];
      *(float4*)&KT[lr][lq*16 + 8]  = vreg[2];
      *(float4*)&KT[lr][lq*16 + 12] = vreg[3];
    }
    if (kt + 1 < nkt) {
      const float* vp = Vp + (size_t)(b * Tkv + (kt + 1) * 64 + lr) * vStride + h * 64 + lq * 16;
      vreg[0] = ((const float4*)vp)[0]; vreg[1] = ((const float4*)vp)[1];
      vreg[2] = ((const float4*)vp)[2]; vreg[3] = ((const float4*)vp)[3];
    }
    __syncthreads();

#pragma unroll
    for (int i = 0; i < 4; ++i) {
      o[i][0] *= alpha[i]; o[i][1] *= alpha[i]; o[i][2] *= alpha[i]; o[i][3] *= alpha[i];
    }
#pragma unroll 8
    for (int c = 0; c < 64; ++c) {
      float4 vv = *(const float4*)&KT[c][tx * 4];
#pragma unroll
      for (int i = 0; i < 4; ++i) {
        float p = Sm[ty*4 + i][c];
        o[i][0] += p * vv.x; o[i][1] += p * vv.y; o[i][2] += p * vv.z; o[i][3] += p * vv.w;
      }
    }
  }

#pragma unroll
  for (int i = 0; i < 4; ++i) {
    float inv = 1.f / l_reg[i];
    float4 r;
    r.x = o[i][0] * inv; r.y = o[i][1] * inv; r.z = o[i][2] * inv; r.w = o[i][3] * inv;
    *(float4*)(Op + (size_t)(b * Tq + qt * 64 + ty * 4 + i) * 256 + h * 64 + tx * 4) = r;
  }
}

// ---------------------------------------------------------------------------
// bf16 MFMA GEMM — unchanged.
// ---------------------------------------------------------------------------
__global__ __launch_bounds__(256) void gemm_bf_k(
    const unsigned short* __restrict__ A, const unsigned short* __restrict__ W,
    const float* __restrict__ bias, unsigned short* __restrict__ C,
    int M, int N, int K, int epi)
{
  __shared__ __align__(16) short As[128 * 32];
  __shared__ __align__(16) short Bs[128 * 32];
  const int tid = threadIdx.x;
  const int lane = tid & 63, w = tid >> 6;
  const int g = lane >> 4, li = lane & 15;
  const int wr = (w >> 1) * 64, wc = (w & 1) * 64;
  const int bm = blockIdx.x * 128, bn = blockIdx.y * 128;

  f32x4 acc[4][4];
#pragma unroll
  for (int m = 0; m < 4; ++m)
#pragma unroll
    for (int n = 0; n < 4; ++n)
      acc[m][n] = (f32x4){0.f, 0.f, 0.f, 0.f};

  const int srow = tid >> 2, scol = (tid & 3) * 8;
  const unsigned short* Ag = A + (size_t)(bm + srow) * K + scol;
  const unsigned short* Wg = W + (size_t)(bn + srow) * K + scol;

  for (int k0 = 0; k0 < K; k0 += 32) {
    __syncthreads();
    GLD16(Ag + k0, &As[tid * 8]);
    GLD16(Ag + k0 + (size_t)64 * K, &As[tid * 8 + 2048]);
    GLD16(Wg + k0, &Bs[tid * 8]);
    GLD16(Wg + k0 + (size_t)64 * K, &Bs[tid * 8 + 2048]);
    __syncthreads();
    short8 af[4], bf[4];
#pragma unroll
    for (int m = 0; m < 4; ++m) af[m] = *(const short8*)&As[(wr + m * 16 + li) * 32 + g * 8];
#pragma unroll
    for (int n = 0; n < 4; ++n) bf[n] = *(const short8*)&Bs[(wc + n * 16 + li) * 32 + g * 8];
#pragma unroll
    for (int m = 0; m < 4; ++m)
#pragma unroll
      for (int n = 0; n < 4; ++n)
        acc[m][n] = __builtin_amdgcn_mfma_f32_16x16x32_bf16(af[m], bf[n], acc[m][n], 0, 0, 0);
  }

#pragma unroll
  for (int m = 0; m < 4; ++m) {
#pragma unroll
    for (int n = 0; n < 4; ++n) {
      int col = bn + wc + n * 16 + li;
      float bv = bias[col];
#pragma unroll
      for (int r = 0; r < 4; ++r) {
        int row = bm + wr + m * 16 + g * 4 + r;
        float v = acc[m][n][r] + bv;
        if (epi == 1) v = 0.5f * v * (1.0f + erff(v * 0.70710678118654752f));
        C[(size_t)row * N + col] = f2bf(v);
      }
    }
  }
}

// ---------------------------------------------------------------------------
// V transpose to global — unchanged.
// ---------------------------------------------------------------------------
__global__ __launch_bounds__(256) void trv_k(
    const unsigned short* __restrict__ V, int vStride,
    unsigned short* __restrict__ VT, int Tkv)
{
  const int kt = blockIdx.x, h = blockIdx.y, b = blockIdx.z;
  __shared__ short t[64][65];
  const int tid = threadIdx.x;
  const int r0 = tid >> 3, seg = tid & 7;
#pragma unroll
  for (int i = 0; i < 2; ++i) {
    int r = r0 + i * 32;
    short8 v = *(const short8*)(V + (size_t)(b * Tkv + kt * 64 + r) * vStride + h * 64 + seg * 8);
    *(short8*)&t[r][seg * 8] = v;
  }
  __syncthreads();
#pragma unroll
  for (int i = 0; i < 2; ++i) {
    int d = r0 + i * 32;
    int k0 = seg * 8;
    short o[8];
#pragma unroll
    for (int j = 0; j < 8; ++j) o[j] = t[k0 + j][d];
    *(short8*)(VT + ((size_t)(b * NH_ + h) * 64 + d) * Tkv + kt * 64 + k0) = *(short8*)o;
  }
}

// ---------------------------------------------------------------------------
// bf16 MFMA flash attention: 48KB LDS, 2 blk/CU (L2-safe), prefetch.
// Used for BOTH SA and CA (the 4-blk variant thrashes L2 — r10, r14).
// ---------------------------------------------------------------------------
__global__ __launch_bounds__(256, 2) void attn_bf_k(
    const unsigned short* __restrict__ Qp, int qStride,
    const unsigned short* __restrict__ Kp, int kStride,
    const unsigned short* __restrict__ VTg,
    unsigned short* __restrict__ Op, int Tq, int Tkv)
{
  int b, h, qt;
  {
    const int nqt = gridDim.x, nh = gridDim.y, nbh = gridDim.y * gridDim.z;
    if ((nbh & 7) == 0) {
      int linear = blockIdx.x + nqt * (blockIdx.y + gridDim.y * blockIdx.z);
      int xcd = linear & 7, idx = linear >> 3;
      int bh = xcd * (nbh >> 3) + idx / nqt;
      qt = idx - (idx / nqt) * nqt;
      h = bh % nh; b = bh / nh;
    } else { qt = blockIdx.x; h = blockIdx.y; b = blockIdx.z; }
  }
  const int tid = threadIdx.x;
  const int lane = tid & 63, w = tid >> 6;
  const int g = lane >> 4, li = lane & 15;

  __shared__ __align__(16) short Qs[128 * 64];
  __shared__ __align__(16) short Ks[64 * 64];
  __shared__ __align__(16) short VTs[64 * 64];
  __shared__ __align__(16) short Ps[128 * 64];

  {
    const int r0 = tid >> 3, seg = tid & 7;
#pragma unroll
    for (int i = 0; i < 4; ++i) {
      int r = r0 + i * 32;
      short8 v = *(const short8*)(Qp + (size_t)(b * Tq + qt * 128 + r) * qStride + h * 64 + seg * 8);
      *(short8*)&Qs[r * 64 + ((seg ^ (r & 7)) << 3)] = v;
    }
  }
  __syncthreads();

  short8 aq[2][2];
#pragma unroll
  for (int m = 0; m < 2; ++m)
#pragma unroll
    for (int ks = 0; ks < 2; ++ks) {
      int row = w * 32 + m * 16 + li;
      aq[m][ks] = *(const short8*)&Qs[row * 64 + (((ks * 4 + g) ^ (row & 7)) << 3)];
    }

  float m_reg[2][4], l_reg[2][4];
  f32x4 o[2][4];
#pragma unroll
  for (int m = 0; m < 2; ++m)
#pragma unroll
    for (int r = 0; r < 4; ++r) { m_reg[m][r] = -INFINITY; l_reg[m][r] = 0.f; }
#pragma unroll
  for (int m = 0; m < 2; ++m)
#pragma unroll
    for (int n = 0; n < 4; ++n) o[m][n] = (f32x4){0.f, 0.f, 0.f, 0.f};

  const int nkt = Tkv >> 6;
  const unsigned short* vt = VTg + (size_t)(b * NH_ + h) * 64 * Tkv;
  const int r0 = tid >> 3, seg = tid & 7;
  const int sr0 = r0, sr1 = r0 + 32;

  short8 kr0, kr1, vr0, vr1;
  kr0 = *(const short8*)(Kp + (size_t)(b * Tkv + sr0) * kStride + h * 64 + seg * 8);
  kr1 = *(const short8*)(Kp + (size_t)(b * Tkv + sr1) * kStride + h * 64 + seg * 8);
  vr0 = *(const short8*)(vt + (size_t)sr0 * Tkv + seg * 8);
  vr1 = *(const short8*)(vt + (size_t)sr1 * Tkv + seg * 8);

  for (int kt = 0; kt < nkt; ++kt) {
    __syncthreads();
    *(short8*)&Ks[sr0 * 64 + ((seg ^ (sr0 & 7)) << 3)] = kr0;
    *(short8*)&Ks[sr1 * 64 + ((seg ^ (sr1 & 7)) << 3)] = kr1;
    *(short8*)&VTs[sr0 * 64 + ((seg ^ (sr0 & 7)) << 3)] = vr0;
    *(short8*)&VTs[sr1 * 64 + ((seg ^ (sr1 & 7)) << 3)] = vr1;
    if (kt + 1 < nkt) {
      int kb = (kt + 1) * 64;
      kr0 = *(const short8*)(Kp + (size_t)(b * Tkv + kb + sr0) * kStride + h * 64 + seg * 8);
      kr1 = *(const short8*)(Kp + (size_t)(b * Tkv + kb + sr1) * kStride + h * 64 + seg * 8);
      vr0 = *(const short8*)(vt + (size_t)sr0 * Tkv + kb + seg * 8);
      vr1 = *(const short8*)(vt + (size_t)sr1 * Tkv + kb + seg * 8);
    }
    __syncthreads();

    f32x4 s[2][4];
    __builtin_amdgcn_s_setprio(1);
#pragma unroll
    for (int m = 0; m < 2; ++m)
#pragma unroll
      for (int n = 0; n < 4; ++n) {
        f32x4 acc = (f32x4){0.f, 0.f, 0.f, 0.f};
#pragma unroll
        for (int ks = 0; ks < 2; ++ks) {
          int key = n * 16 + li;
          short8 bk = *(const short8*)&Ks[key * 64 + (((ks * 4 + g) ^ (key & 7)) << 3)];
          acc = __builtin_amdgcn_mfma_f32_16x16x32_bf16(aq[m][ks], bk, acc, 0, 0, 0);
        }
        s[m][n] = acc * 0.125f;
      }
    __builtin_amdgcn_s_setprio(0);

    float alpha[2][4];
#pragma unroll
    for (int m = 0; m < 2; ++m)
#pragma unroll
      for (int r = 0; r < 4; ++r) {
        float pm = fmaxf(fmaxf(s[m][0][r], s[m][1][r]), fmaxf(s[m][2][r], s[m][3][r]));
#pragma unroll
        for (int off = 1; off < 16; off <<= 1) pm = fmaxf(pm, __shfl_xor(pm, off));
        float mn = fmaxf(m_reg[m][r], pm);
        alpha[m][r] = __expf(m_reg[m][r] - mn);
        float ls = 0.f;
        int row = w * 32 + m * 16 + g * 4 + r;
#pragma unroll
        for (int n = 0; n < 4; ++n) {
          float p = __expf(s[m][n][r] - mn);
          ls += p;
          int col = n * 16 + li;
          Ps[row * 64 + (col ^ ((row & 7) << 3))] = (short)f2bf(p);
        }
#pragma unroll
        for (int off = 1; off < 16; off <<= 1) ls += __shfl_xor(ls, off);
        l_reg[m][r] = l_reg[m][r] * alpha[m][r] + ls;
        m_reg[m][r] = mn;
      }

#pragma unroll
    for (int m = 0; m < 2; ++m) {
      f32x4 al = (f32x4){alpha[m][0], alpha[m][1], alpha[m][2], alpha[m][3]};
#pragma unroll
      for (int n = 0; n < 4; ++n) o[m][n] *= al;
    }
    short8 ap[2][2];
#pragma unroll
    for (int m = 0; m < 2; ++m)
#pragma unroll
      for (int ks = 0; ks < 2; ++ks) {
        int row = w * 32 + m * 16 + li;
        ap[m][ks] = *(const short8*)&Ps[row * 64 + (((ks * 4 + g) ^ (row & 7)) << 3)];
      }
    __builtin_amdgcn_s_setprio(1);
#pragma unroll
    for (int m = 0; m < 2; ++m)
#pragma unroll
      for (int n = 0; n < 4; ++n)
#pragma unroll
        for (int ks = 0; ks < 2; ++ks) {
          int d = n * 16 + li;
          short8 bv = *(const short8*)&VTs[d * 64 + (((ks * 4 + g) ^ (d & 7)) << 3)];
          o[m][n] = __builtin_amdgcn_mfma_f32_16x16x32_bf16(ap[m][ks], bv, o[m][n], 0, 0, 0);
        }
    __builtin_amdgcn_s_setprio(0);
  }

#pragma unroll
  for (int m = 0; m < 2; ++m)
#pragma unroll
    for (int n = 0; n < 4; ++n)
#pragma unroll
      for (int r = 0; r < 4; ++r) {
        float v = o[m][n][r] / l_reg[m][r];
        Op[(size_t)(b * Tq + qt * 128 + w * 32 + m * 16 + g * 4 + r) * 256 + h * 64 + n * 16 + li] = f2bf(v);
      }
}

// LayerNorm f32 (encoder/vpred) — unchanged.
__global__ __launch_bounds__(256) void addln_k(
    const float* __restrict__ X, const float* __restrict__ R,
    const float* __restrict__ w, const float* __restrict__ bias,
    float* __restrict__ Out, int rows)
{
  int tid = threadIdx.x, wv = tid >> 6, ln = tid & 63;
  int row = blockIdx.x * 4 + wv;
  if (row >= rows) return;
  const float* xp = X + (size_t)row * 256;
  float v[4];
#pragma unroll
  for (int u = 0; u < 4; ++u) v[u] = xp[u * 64 + ln];
  if (R) {
    const float* rp = R + (size_t)row * 256;
#pragma unroll
    for (int u = 0; u < 4; ++u) v[u] += rp[u * 64 + ln];
  }
  float s = v[0] + v[1] + v[2] + v[3];
#pragma unroll
  for (int off = 1; off < 64; off <<= 1) s += __shfl_xor(s, off);
  float mean = s * (1.f / 256.f);
  float c[4], sq = 0.f;
#pragma unroll
  for (int u = 0; u < 4; ++u) { c[u] = v[u] - mean; sq += c[u] * c[u]; }
#pragma unroll
  for (int off = 1; off < 64; off <<= 1) sq += __shfl_xor(sq, off);
  float rs = 1.f / sqrtf(sq * (1.f / 256.f) + 1e-5f);
  float* op = Out + (size_t)row * 256;
#pragma unroll
  for (int u = 0; u < 4; ++u)
    op[u * 64 + ln] = c[u] * rs * w[u * 64 + ln] + bias[u * 64 + ln];
}

// Decoder LayerNorm: bf16 state + bf16 residual -> bf16 state (f32 math).
__global__ __launch_bounds__(256) void addlnb_k(
    unsigned short* __restrict__ Xbf, const unsigned short* __restrict__ Rbf,
    const float* __restrict__ w, const float* __restrict__ bias, int rows)
{
  int tid = threadIdx.x, wv = tid >> 6, ln = tid & 63;
  int row = blockIdx.x * 4 + wv;
  if (row >= rows) return;
  unsigned short* xp = Xbf + (size_t)row * 256;
  const unsigned short* rp = Rbf + (size_t)row * 256;
  float v[4];
#pragma unroll
  for (int u = 0; u < 4; ++u) v[u] = bf2f(xp[u * 64 + ln]) + bf2f(rp[u * 64 + ln]);
  float s = v[0] + v[1] + v[2] + v[3];
#pragma unroll
  for (int off = 1; off < 64; off <<= 1) s += __shfl_xor(s, off);
  float mean = s * (1.f / 256.f);
  float c[4], sq = 0.f;
#pragma unroll
  for (int u = 0; u < 4; ++u) { c[u] = v[u] - mean; sq += c[u] * c[u]; }
#pragma unroll
  for (int off = 1; off < 64; off <<= 1) sq += __shfl_xor(sq, off);
  float rs = 1.f / sqrtf(sq * (1.f / 256.f) + 1e-5f);
#pragma unroll
  for (int u = 0; u < 4; ++u) {
    float y = c[u] * rs * w[u * 64 + ln] + bias[u * 64 + ln];
    xp[u * 64 + ln] = f2bf(y);
  }
}

// Conv1d k=3 pad=1 — unchanged (r12 vectorized).
__global__ __launch_bounds__(256) void conv_k(
    const float* __restrict__ X, const float* __restrict__ Wt,
    const float* __restrict__ bias, float* __restrict__ Yo, int relu)
{
  const int b = blockIdx.z;
  const int o0 = blockIdx.y * 64, t0 = blockIdx.x * 64;
  const int tid = threadIdx.x, tx = tid & 15, ty = tid >> 4;
  __shared__ __align__(16) float xs[16][68];
  __shared__ __align__(16) float ws_s[64][48];
  float acc[4][4] = {{0.f,0.f,0.f,0.f},{0.f,0.f,0.f,0.f},{0.f,0.f,0.f,0.f},{0.f,0.f,0.f,0.f}};
  for (int i0 = 0; i0 < 256; i0 += 16) {
    for (int idx = tid; idx < 16 * 68; idx += 256) {
      int ic = idx / 68, tt = idx - ic * 68;
      int t = t0 + tt - 1;
      xs[ic][tt] = (tt < 66 && t >= 0 && t < 256)
                       ? X[((size_t)b * 256 + (i0 + ic)) * 256 + t] : 0.f;
    }
    for (int f4 = tid; f4 < 768; f4 += 256) {
      int oo = f4 / 12, seg = f4 - oo * 12;
      float4 v = *(const float4*)(Wt + (size_t)(o0 + oo) * 768 + i0 * 3 + seg * 4);
      *(float4*)&ws_s[oo][seg * 4] = v;
    }
    __syncthreads();
#pragma unroll
    for (int ic = 0; ic < 16; ++ic) {
      float4 xa = *(const float4*)&xs[ic][tx * 4];
      float4 xb = *(const float4*)&xs[ic][tx * 4 + 4];
      float xr[6] = {xa.x, xa.y, xa.z, xa.w, xb.x, xb.y};
#pragma unroll
      for (int i = 0; i < 4; ++i) {
        const float* wr = &ws_s[ty * 4 + i][ic * 3];
        float w0 = wr[0], w1 = wr[1], w2 = wr[2];
#pragma unroll
        for (int j = 0; j < 4; ++j)
          acc[i][j] += w0 * xr[j] + w1 * xr[j + 1] + w2 * xr[j + 2];
      }
    }
    __syncthreads();
  }
#pragma unroll
  for (int i = 0; i < 4; ++i) {
    int oo = o0 + ty * 4 + i;
    float bv = bias[oo];
#pragma unroll
    for (int j = 0; j < 4; ++j) {
      float v = acc[i][j] + bv;
      if (relu) v = fmaxf(v, 0.f);
      Yo[((size_t)b * 256 + oo) * 256 + t0 + tx * 4 + j] = v;
    }
  }
}

__global__ void transp_k(const float* __restrict__ In, float* __restrict__ Out)
{
  int b = blockIdx.z, t0 = blockIdx.x * 32, d0 = blockIdx.y * 32;
  __shared__ float tile[32][33];
  int tx = threadIdx.x, ty = threadIdx.y;
#pragma unroll
  for (int q = 0; q < 4; ++q)
    tile[ty + q * 8][tx] = In[((size_t)b * 256 + t0 + ty + q * 8) * 256 + d0 + tx];
  __syncthreads();
#pragma unroll
  for (int q = 0; q < 4; ++q)
    Out[((size_t)b * 256 + d0 + ty + q * 8) * 256 + t0 + tx] = tile[tx][ty + q * 8];
}

__global__ __launch_bounds__(256) void rowdot_k(
    const float* __restrict__ H, const float* __restrict__ lw,
    const float* __restrict__ lb, float* __restrict__ of32,
    float* __restrict__ oout, int rows)
{
  int tid = threadIdx.x, wv = tid >> 6, ln = tid & 63;
  int row = blockIdx.x * 4 + wv;
  if (row >= rows) return;
  const float* hp = H + (size_t)row * 256;
  float s = 0.f;
#pragma unroll
  for (int u = 0; u < 4; ++u) s += hp[u * 64 + ln] * lw[u * 64 + ln];
#pragma unroll
  for (int off = 1; off < 64; off <<= 1) s += __shfl_xor(s, off);
  if (ln == 0) {
    float v = s + lb[0];
    of32[row] = v;
    oout[row] = v;
  }
}

__global__ void maxlen_k(const float* __restrict__ dur, int* __restrict__ ml)
{
  __shared__ float rnds[32];
  int tid = threadIdx.x, wv = tid >> 6, ln = tid & 63;
  for (int b = wv; b < 32; b += 4) {
    const float* dp = dur + (size_t)b * 256;
    float s = dp[ln] + dp[64 + ln] + dp[128 + ln] + dp[192 + ln];
#pragma unroll
    for (int off = 1; off < 64; off <<= 1) s += __shfl_xor(s, off);
    if (ln == 0) rnds[b] = rintf(s);
  }
  __syncthreads();
  if (tid == 0) {
    float m = rnds[0];
    for (int b = 1; b < 32; ++b) m = fmaxf(m, rnds[b]);
    int v = (int)m;
    v = v < 0 ? 0 : (v > MAXBUF_ ? MAXBUF_ : v);
    *ml = v;
  }
}

__global__ void reg_k(const float* __restrict__ dur, const int* __restrict__ lens,
                      const int* __restrict__ ml, int* __restrict__ tok)
{
  int b = blockIdx.x;
  __shared__ float sdur[256];
  __shared__ int ends[256];
  int tid = threadIdx.x;
  sdur[tid] = dur[(size_t)b * 256 + tid];
  __syncthreads();
  if (tid == 0) {
    int maxlen = *ml, len = lens[b], pos = 0;
    for (int t = 0; t < 256; ++t) {
      int d = (int)rintf(sdur[t]);
      bool ok = (t < len) && (d > 0) && (pos + d <= maxlen);
      if (ok) pos += d;
      ends[t] = pos;
    }
  }
  __syncthreads();
  int total = ends[255];
  for (int f = tid; f < MAXBUF_; f += 256) {
    int lo = 0, hi = 256;
    while (lo < hi) { int mid = (lo + hi) >> 1; if (ends[mid] <= f) lo = mid + 1; else hi = mid; }
    int tc = lo > 255 ? 255 : lo;
    tok[(size_t)b * MAXBUF_ + f] = (f < total) ? tc : -1;
  }
}

// Y[b,f,:] = tok>=0 ? bf16(enc[b,tok,:]) : 0  (bf16 state)
__global__ void gatherb_k(const float* __restrict__ enc, const int* __restrict__ tok,
                          unsigned short* __restrict__ Ybf)
{
  int rf = blockIdx.x;
  int b = rf >> 10;
  int t = tok[rf];
  unsigned short* dst = Ybf + (size_t)rf * 256;
  int ln = threadIdx.x;
  if (t >= 0) {
    float4 v = ((const float4*)(enc + ((size_t)b * 256 + t) * 256))[ln];
    unsigned short o[4] = {f2bf(v.x), f2bf(v.y), f2bf(v.z), f2bf(v.w)};
    *(ushort4*)(dst + ln * 4) = *(ushort4*)o;
  } else {
    unsigned short o[4] = {0, 0, 0, 0};
    *(ushort4*)(dst + ln * 4) = *(ushort4*)o;
  }
}

// MEL (B*1024, 80) -> out (B, 80, 1024) via LDS tile transpose
__global__ __launch_bounds__(256) void meltr_k(
    const float* __restrict__ MEL, float* __restrict__ out)
{
  int b = blockIdx.z, m0 = blockIdx.y * 16, f0 = blockIdx.x * 64;
  __shared__ float t[16][65];
  int tid = threadIdx.x;
  {
    int f_i = tid >> 4, m_i = tid & 15;
#pragma unroll
    for (int q = 0; q < 4; ++q)
      t[m_i][f_i + q * 16] = MEL[((size_t)b * 1024 + f0 + f_i + q * 16) * 80 + m0 + m_i];
  }
  __syncthreads();
  {
    int f = tid & 63, my = tid >> 6;
#pragma unroll
    for (int q = 0; q < 4; ++q) {
      int m = my * 4 + q;
      out[((size_t)b * NMEL_ + m0 + m) * MAXBUF_ + f0 + f] = t[m][f];
    }
  }
}

// ============================================================================
extern "C" void kernel_launch(void* const* d_in, const int* in_sizes, int n_in,
                              void* d_out, int out_size, void* d_ws, size_t ws_size,
                              hipStream_t stream)
{
  (void)in_sizes; (void)n_in; (void)out_size;

  const float* te   = (const float*)d_in[0];
  const int*   lens = (const int*)d_in[1];
  const float* e_qkv_w = (const float*)d_in[2];
  const float* e_qkv_b = (const float*)d_in[3];
  const float* e_out_w = (const float*)d_in[4];
  const float* e_out_b = (const float*)d_in[5];
  const float* e_ln1_w = (const float*)d_in[6];
  const float* e_ln1_b = (const float*)d_in[7];
  const float* e_ff1_w = (const float*)d_in[8];
  const float* e_ff1_b = (const float*)d_in[9];
  const float* e_ff2_w = (const float*)d_in[10];
  const float* e_ff2_b = (const float*)d_in[11];
  const float* e_ln2_w = (const float*)d_in[12];
  const float* e_ln2_b = (const float*)d_in[13];
  const float* c1w = (const float*)d_in[14];
  const float* c1b = (const float*)d_in[15];
  const float* l1w = (const float*)d_in[16];
  const float* l1b = (const float*)d_in[17];
  const float* c2w = (const float*)d_in[18];
  const float* c2b = (const float*)d_in[19];
  const float* l2w = (const float*)d_in[20];
  const float* l2b = (const float*)d_in[21];
  const float* linw = (const float*)d_in[22];
  const float* linb = (const float*)d_in[23];
  const float* d_sa_qkv_w = (const float*)d_in[24];
  const float* d_sa_qkv_b = (const float*)d_in[25];
  const float* d_sa_out_w = (const float*)d_in[26];
  const float* d_sa_out_b = (const float*)d_in[27];
  const float* d_ca_qkv_w = (const float*)d_in[28];
  const float* d_ca_qkv_b = (const float*)d_in[29];
  const float* d_ca_out_w = (const float*)d_in[30];
  const float* d_ca_out_b = (const float*)d_in[31];
  const float* d_ln1_w = (const float*)d_in[32];
  const float* d_ln1_b = (const float*)d_in[33];
  const float* d_ln2_w = (const float*)d_in[34];
  const float* d_ln2_b = (const float*)d_in[35];
  const float* d_ln3_w = (const float*)d_in[36];
  const float* d_ln3_b = (const float*)d_in[37];
  const float* d_ff1_w = (const float*)d_in[38];
  const float* d_ff1_b = (const float*)d_in[39];
  const float* d_ff2_w = (const float*)d_in[40];
  const float* d_ff2_b = (const float*)d_in[41];
  const float* melw = (const float*)d_in[42];
  const float* melb = (const float*)d_in[43];
  float* out = (float*)d_out;   // f32: mel | duration | pitch | energy

  // ---- arena ----
  char* p = (char*)d_ws;
  float* Y   = (float*)p;            p += 8388608ull * 4;    // split-K partials / vpred scratch
  float* ENC = (float*)p;            p += 2097152ull * 4;
  unsigned short* ENCbf = (unsigned short*)p; p += 2097152ull * 2;
  unsigned short* Wsaqkv = (unsigned short*)p; p += 786432ull * 2;
  unsigned short* Wsaout = (unsigned short*)p; p += 262144ull * 2;
  unsigned short* Wcaqkv = (unsigned short*)p; p += 786432ull * 2;
  unsigned short* Wcaout = (unsigned short*)p; p += 262144ull * 2;
  unsigned short* Wff1   = (unsigned short*)p; p += 1048576ull * 2;
  unsigned short* Wff2   = (unsigned short*)p; p += 1048576ull * 2;
  float* DUR = (float*)p;            p += 24576ull * 4;
  int* TOK   = (int*)p;              p += 32768ull * 4;
  int* MAXL  = (int*)p;              p += 4096;
  size_t fixed_b = (size_t)(p - (char*)d_ws);

  int grp = 1;
  {
    const int cand[6] = {32, 16, 8, 4, 2, 1};
    for (int c = 0; c < 6; ++c) {
      if (fixed_b + (size_t)cand[c] * 1835008ull * 2 <= ws_size) { grp = cand[c]; break; }
    }
  }
  unsigned short* REG = (unsigned short*)p;
  unsigned short* Ybf   = REG;
  unsigned short* ADDbf = REG + (size_t)grp * 262144;
  unsigned short* AObf  = REG + (size_t)grp * 524288;
  unsigned short* UN    = REG + (size_t)grp * 786432;
  unsigned short* VTb   = REG + (size_t)grp * 1572864;
  int grp_e = grp * 2 > 32 ? 32 : grp * 2;
  float* P0e = (float*)REG;
  float* P1e = P0e + (size_t)grp_e * 262144;
  float* P2e = P1e + (size_t)grp_e * 65536;
  float* ENCT = Y;
  float* H1   = Y + 2097152;
  float* H2   = Y + 4194304;
  float* MEL  = ENC;

  auto gemm2s = [&](const float* A, const float* W, const float* bias, float* C,
                    int M, int N, int K, int S, int epi) {
    int kChunk = K / S;
    gemm2p_k<<<dim3(M / 128, N / 128, S), dim3(256), 0, stream>>>(
        A, W, C, Y, M, N, kChunk, K);
    size_t MN = (size_t)M * N;
    rsum_k<<<dim3((unsigned)(MN / 1024)), dim3(256), 0, stream>>>(
        C, Y, bias, S - 1, N, MN, epi);
  };
  auto gemm_bf = [&](const unsigned short* A, const unsigned short* W, const float* bias,
                     unsigned short* C, int M, int N, int K, int epi) {
    dim3 g(M / 128, N / 128);
    gemm_bf_k<<<g, dim3(256), 0, stream>>>(A, W, bias, C, M, N, K, epi);
  };
  auto addln = [&](const float* X, const float* R, const float* w, const float* b,
                   float* O, int rows) {
    addln_k<<<dim3((rows + 3) / 4), dim3(256), 0, stream>>>(X, R, w, b, O, rows);
  };
  auto addlnb = [&](unsigned short* Xbf, const unsigned short* Rbf, const float* w,
                    const float* b, int rows) {
    addlnb_k<<<dim3((rows + 3) / 4), dim3(256), 0, stream>>>(Xbf, Rbf, w, b, rows);
  };
  auto cvt = [&](const float* in, unsigned short* o, int n) {
    cvt_k<<<dim3(n / 1024), dim3(256), 0, stream>>>(in, o, n);
  };

  // ---- convert decoder weights to bf16 (once) ----
  cvt(d_sa_qkv_w, Wsaqkv, 786432);
  cvt(d_sa_out_w, Wsaout, 262144);
  cvt(d_ca_qkv_w, Wcaqkv, 786432);
  cvt(d_ca_out_w, Wcaout, 262144);
  cvt(d_ff1_w, Wff1, 1048576);
  cvt(d_ff2_w, Wff2, 1048576);

  // ================= encoder (fp32; split-K on starved GEMMs) =============
  for (int i = 0; i < 4; ++i) {
    for (int g0 = 0; g0 < B_; g0 += grp_e) {
      int rows = grp_e * T_;
      const size_t off = (size_t)g0 * T_ * D_;
      const float* xin = (i == 0) ? te + off : ENC + off;
      gemm2s(xin, e_qkv_w + (size_t)i * 196608, e_qkv_b + i * 768, P0e, rows, 768, 256, 2, 0);
      attn_k<<<dim3(T_ / 64, NH_, grp_e), dim3(256), 0, stream>>>(
          P0e, 768, P0e + 256, 768, P0e + 512, 768, P1e, T_, T_, lens + g0);
      gemm2s(P1e, e_out_w + (size_t)i * 65536, e_out_b + i * 256, P2e, rows, 256, 256, 4, 0);
      addln(xin, P2e, e_ln1_w + i * 256, e_ln1_b + i * 256, ENC + off, rows);
      gemm2s(ENC + off, e_ff1_w + (size_t)i * 262144, e_ff1_b + i * 1024, P0e, rows, 1024, 256, 2, 1);
      gemm2s(P0e, e_ff2_w + (size_t)i * 262144, e_ff2_b + i * 256, P2e, rows, 256, 1024, 4, 0);
      addln(ENC + off, P2e, e_ln2_w + i * 256, e_ln2_b + i * 256, ENC + off, rows);
    }
  }
  cvt(ENC, ENCbf, 2097152);

  // ================= variance predictors (fp32) =================
  transp_k<<<dim3(8, 8, B_), dim3(32, 8), 0, stream>>>(ENC, ENCT);
  for (int j = 0; j < 3; ++j) {
    conv_k<<<dim3(4, 4, B_), dim3(256), 0, stream>>>(
        ENCT, c1w + (size_t)j * 196608, c1b + j * 256, H1, 1);
    addln(H1, nullptr, l1w + j * 256, l1b + j * 256, H1, B_ * T_);
    conv_k<<<dim3(4, 4, B_), dim3(256), 0, stream>>>(
        H1, c2w + (size_t)j * 196608, c2b + j * 256, H2, 1);
    addln(H2, nullptr, l2w + j * 256, l2b + j * 256, H2, B_ * T_);
    rowdot_k<<<dim3(B_ * T_ / 4), dim3(256), 0, stream>>>(
        H2, linw + j * 256, linb + j, DUR + (size_t)j * 8192,
        out + 2621440 + (size_t)j * 8192, B_ * T_);
  }

  // ================= length regulator =================
  maxlen_k<<<dim3(1), dim3(256), 0, stream>>>(DUR, MAXL);
  reg_k<<<dim3(B_), dim3(256), 0, stream>>>(DUR, lens, MAXL, TOK);
  gatherb_k<<<dim3(B_ * MAXBUF_), dim3(64), 0, stream>>>(ENC, TOK, Ybf);

  // ================= decoder (bf16 MFMA; bf16 residual state) =============
  for (int i = 0; i < 4; ++i) {
    for (int g0 = 0; g0 < B_; g0 += grp) {
      int rows = grp * MAXBUF_;
      // self-attention
      gemm_bf(Ybf, Wsaqkv + (size_t)i * 196608, d_sa_qkv_b + i * 768, UN, rows, 768, 256, 0);
      trv_k<<<dim3(MAXBUF_ / 64, NH_, grp), dim3(256), 0, stream>>>(UN + 512, 768, VTb, MAXBUF_);
      attn_bf_k<<<dim3(MAXBUF_ / 128, NH_, grp), dim3(256), 0, stream>>>(
          UN, 768, UN + 256, 768, VTb, AObf, MAXBUF_, MAXBUF_);
      gemm_bf(AObf, Wsaout + (size_t)i * 65536, d_sa_out_b + i * 256, ADDbf, rows, 256, 256, 0);
      addlnb(Ybf, ADDbf, d_ln1_w + i * 256, d_ln1_b + i * 256, rows);
      // cross-attention (2 blk/CU L2-safe kernel)
      gemm_bf(Ybf, Wcaqkv + (size_t)i * 196608, d_ca_qkv_b + i * 768, UN, rows, 256, 256, 0);
      gemm_bf(ENCbf + (size_t)g0 * 65536, Wcaqkv + (size_t)i * 196608 + 65536,
              d_ca_qkv_b + i * 768 + 256, UN + (size_t)grp * 262144, grp * T_, 512, 256, 0);
      trv_k<<<dim3(T_ / 64, NH_, grp), dim3(256), 0, stream>>>(
          UN + (size_t)grp * 262144 + 256, 512, VTb, T_);
      attn_bf_k<<<dim3(MAXBUF_ / 128, NH_, grp), dim3(256), 0, stream>>>(
          UN, 256, UN + (size_t)grp * 262144, 512, VTb, AObf, MAXBUF_, T_);
      gemm_bf(AObf, Wcaout + (size_t)i * 65536, d_ca_out_b + i * 256, ADDbf, rows, 256, 256, 0);
      addlnb(Ybf, ADDbf, d_ln2_w + i * 256, d_ln2_b + i * 256, rows);
      // feed-forward
      gemm_bf(Ybf, Wff1 + (size_t)i * 262144, d_ff1_b + i * 1024, UN, rows, 1024, 256, 1);
      gemm_bf(UN, Wff2 + (size_t)i * 262144, d_ff2_b + i * 256, ADDbf, rows, 256, 1024, 0);
      addlnb(Ybf, ADDbf, d_ln3_w + i * 256, d_ln3_b + i * 256, rows);
    }
  }

  // ================= mel head: bf16-A gemm + transpose =================
  gemm_kb_k<<<dim3((B_ * MAXBUF_ + 63) / 64, (NMEL_ + 63) / 64), dim3(256), 0, stream>>>(
      Ybf, melw, melb, MEL, B_ * MAXBUF_, NMEL_, 256);
  meltr_k<<<dim3(16, 5, B_), dim3(256), 0, stream>>>(MEL, out);
}